// Round 1
// baseline (3704.253 us; speedup 1.0000x reference)
//
#include <hip/hip_runtime.h>
#include <math.h>

// ---------------------------------------------------------------------------
// AdaptiveWindowAttention — round 1: correct f32 baseline
// B=2 S=2048 EMB=2048 H=16 D=128; window in [64,256] (sigmoid-bounded)
//
// Pipeline:
//  1. memset ws scalar/xmean area
//  2. rope_table: cos/sin (S x D) in f64 -> f32 tables
//  3. col_reduce: per-batch sum/sumsq (f64 atomics) + column sums for x_mean
//  4. hidden_kernel: silu(x_mean @ w_c1.T)  (f64 accum)
//  5. window_kernel: learned/var_norm -> window int (trunc, clamp) in ws
//  6. gemm_qkv: x @ w_qkv.T -> q/k/v buffers in (B,H,S,D) layout
//  7. rope_apply: in-place rope on q,k
//  8. attn_kernel: one block per (b,h,q); <=256 keys; LDS softmax
//  9. gemm_out: gather (B,H,S,D)->(M,K) @ w_out.T -> d_out
// ---------------------------------------------------------------------------

#define S_LEN 2048
#define EMB 2048
#define HEADS 16
#define HDIM 128

// ---------------- rope tables ----------------
__global__ void rope_table(float* __restrict__ ctab, float* __restrict__ stab) {
    int s = blockIdx.x;        // 0..2047
    int d = threadIdx.x;       // 0..127
    int j = d & 63;            // freq index: d<64 -> d ; d>=64 -> d-64
    double inv = pow(10000.0, -(double)j / 64.0);
    double ang = (double)s * inv;
    ctab[s * HDIM + d] = (float)cos(ang);
    stab[s * HDIM + d] = (float)sin(ang);
}

// ---------------- batch stats ----------------
__global__ __launch_bounds__(256) void col_reduce(const float* __restrict__ x,
                                                  float* __restrict__ xmean_acc,
                                                  double* __restrict__ scal) {
    int b = blockIdx.z;      // batch
    int cg = blockIdx.x;     // column group (8)
    int sg = blockIdx.y;     // row chunk (8)
    int e = cg * 256 + threadIdx.x;
    const float* xb = x + ((size_t)b * S_LEN + sg * 256) * EMB;
    double csum = 0.0, csq = 0.0;
    for (int s = 0; s < 256; ++s) {
        float v = xb[(size_t)s * EMB + e];
        csum += v;
        csq += (double)v * (double)v;
    }
    atomicAdd(xmean_acc + b * EMB + e, (float)csum);
    __shared__ double rs[256], rq[256];
    rs[threadIdx.x] = csum; rq[threadIdx.x] = csq;
    __syncthreads();
    for (int off = 128; off > 0; off >>= 1) {
        if (threadIdx.x < off) {
            rs[threadIdx.x] += rs[threadIdx.x + off];
            rq[threadIdx.x] += rq[threadIdx.x + off];
        }
        __syncthreads();
    }
    if (threadIdx.x == 0) {
        atomicAdd(&scal[b], rs[0]);
        atomicAdd(&scal[2 + b], rq[0]);
    }
}

// hidden[b][j] = silu( (x_mean[b,:] @ w_c1[j,:]) )
__global__ __launch_bounds__(256) void hidden_kernel(const float* __restrict__ xmean_acc,
                                                     const float* __restrict__ wc1,
                                                     float* __restrict__ hidden) {
    int j = blockIdx.x;   // 0..511
    int b = blockIdx.y;   // 0..1
    const float* xm = xmean_acc + b * EMB;
    const float* wr = wc1 + (size_t)j * EMB;
    double acc = 0.0;
    for (int k = threadIdx.x; k < EMB; k += 256)
        acc += (double)xm[k] * (double)wr[k];
    __shared__ double red[256];
    red[threadIdx.x] = acc;
    __syncthreads();
    for (int off = 128; off > 0; off >>= 1) {
        if (threadIdx.x < off) red[threadIdx.x] += red[threadIdx.x + off];
        __syncthreads();
    }
    if (threadIdx.x == 0) {
        double z = red[0] * (1.0 / 2048.0);    // x_mean = colsum / S
        hidden[b * 512 + j] = (float)(z / (1.0 + exp(-z)));
    }
}

__global__ __launch_bounds__(512) void window_kernel(const float* __restrict__ hidden,
                                                     const float* __restrict__ wc2,
                                                     const double* __restrict__ scal,
                                                     int* __restrict__ wout) {
    __shared__ double red[512];
    __shared__ double wfs[2];
    for (int b = 0; b < 2; ++b) {
        red[threadIdx.x] = (double)hidden[b * 512 + threadIdx.x] * (double)wc2[threadIdx.x];
        __syncthreads();
        for (int off = 256; off > 0; off >>= 1) {
            if (threadIdx.x < off) red[threadIdx.x] += red[threadIdx.x + off];
            __syncthreads();
        }
        if (threadIdx.x == 0) {
            double pre = red[0];
            double learned = 1.0 / (1.0 + exp(-pre));
            const double N = (double)S_LEN * (double)EMB;
            double sum = scal[b], sq = scal[2 + b];
            double var = (sq - sum * sum / N) / (N - 1.0);
            double vn = 1.0 / (1.0 + exp(-(var * 10.0 - 5.0)));
            double comp = 0.5 * (vn + learned);
            wfs[b] = 64.0 + comp * 192.0;
        }
        __syncthreads();
    }
    if (threadIdx.x == 0) {
        float wf = (float)(0.5 * (wfs[0] + wfs[1]));  // f32 mean like jnp
        int w = (int)wf;                               // astype(int32) truncates
        if (w > S_LEN) w = S_LEN;
        if (w < 64) w = 64;
        *wout = w;
    }
}

// ---------------- GEMM qkv: C[m,n] = sum_k x[m,k] * w_qkv[n,k] ----------------
// M=4096 N=6144 K=2048. Writes into q/k/v (B,H,S,D) buffers.
#define BK 16
__global__ __launch_bounds__(256) void gemm_qkv(const float* __restrict__ A,
                                                const float* __restrict__ Bm,
                                                float* __restrict__ qb,
                                                float* __restrict__ kb,
                                                float* __restrict__ vb) {
    __shared__ float As[BK][64 + 1];
    __shared__ float Bs[BK][64 + 1];
    const int tid = threadIdx.x;
    const int m0 = blockIdx.y * 64;
    const int n0 = blockIdx.x * 64;
    const int lr = tid >> 2;          // 0..63
    const int lc = (tid & 3) * 4;     // 0,4,8,12
    const int tx = tid & 15, ty = tid >> 4;
    const int K = EMB;
    float acc[4][4] = {};
    for (int k0 = 0; k0 < K; k0 += BK) {
        float4 av = *(const float4*)(A + (size_t)(m0 + lr) * K + k0 + lc);
        float4 bv = *(const float4*)(Bm + (size_t)(n0 + lr) * K + k0 + lc);
        __syncthreads();
        As[lc + 0][lr] = av.x; As[lc + 1][lr] = av.y; As[lc + 2][lr] = av.z; As[lc + 3][lr] = av.w;
        Bs[lc + 0][lr] = bv.x; Bs[lc + 1][lr] = bv.y; Bs[lc + 2][lr] = bv.z; Bs[lc + 3][lr] = bv.w;
        __syncthreads();
#pragma unroll
        for (int kk = 0; kk < BK; ++kk) {
            float a[4], bf[4];
#pragma unroll
            for (int i = 0; i < 4; ++i) a[i] = As[kk][ty * 4 + i];
#pragma unroll
            for (int j = 0; j < 4; ++j) bf[j] = Bs[kk][tx * 4 + j];
#pragma unroll
            for (int i = 0; i < 4; ++i)
#pragma unroll
                for (int j = 0; j < 4; ++j)
                    acc[i][j] = fmaf(a[i], bf[j], acc[i][j]);
        }
    }
    // epilogue: n -> (which, h, d); whole 64-wide tile shares which & h
    const int which = n0 >> 11;
    const int h = (n0 >> 7) & 15;
    float* dst = which == 0 ? qb : (which == 1 ? kb : vb);
    const int d0 = (n0 & 127) + tx * 4;
#pragma unroll
    for (int i = 0; i < 4; ++i) {
        int m = m0 + ty * 4 + i;
        int b = m >> 11, s = m & 2047;
        size_t rowbase = (((size_t)b * HEADS + h) * S_LEN + s) * HDIM;
#pragma unroll
        for (int j = 0; j < 4; ++j)
            dst[rowbase + d0 + j] = acc[i][j];
    }
}

// ---------------- rope in place on q,k ----------------
__global__ __launch_bounds__(256) void rope_apply(float* __restrict__ qb, float* __restrict__ kb,
                                                  const float* __restrict__ ctab,
                                                  const float* __restrict__ stab) {
    size_t idx = (size_t)blockIdx.x * 256 + threadIdx.x;  // pair index, B*H*S*64 total
    int i = idx & 63;
    int s = (int)((idx >> 6) & 2047);
    size_t bh = idx >> 17;
    int d0 = i * 2;
    size_t base = (bh * S_LEN + s) * HDIM + d0;
    float c0 = ctab[s * HDIM + d0], c1 = ctab[s * HDIM + d0 + 1];
    float s0 = stab[s * HDIM + d0], s1 = stab[s * HDIM + d0 + 1];
    float2 q = *(float2*)(qb + base);
    float2 k = *(float2*)(kb + base);
    float2 qn, kn;
    qn.x = q.x * c0 - q.y * s0;  qn.y = q.y * c1 + q.x * s1;
    kn.x = k.x * c0 - k.y * s0;  kn.y = k.y * c1 + k.x * s1;
    *(float2*)(qb + base) = qn;
    *(float2*)(kb + base) = kn;
}

// ---------------- attention: one block per (b,h,q) ----------------
__global__ __launch_bounds__(256) void attn_kernel(const float* __restrict__ qb,
                                                   const float* __restrict__ kb,
                                                   const float* __restrict__ vb,
                                                   float* __restrict__ ob,
                                                   const int* __restrict__ wptr) {
    const int qpos = blockIdx.x;
    const int h = blockIdx.y;
    const int b = blockIdx.z;
    const int tid = threadIdx.x;
    int window = *wptr;
    if (window > 256) window = 256;  // sigmoid bound guarantees <=256 anyway
    int start = qpos - window + 1; if (start < 0) start = 0;
    const int count = qpos - start + 1;   // 1..256

    __shared__ float qs[HDIM];
    __shared__ float sc[256];
    __shared__ float red[256];
    const size_t bh = ((size_t)b * HEADS + h) * S_LEN;
    if (tid < HDIM) qs[tid] = qb[(bh + qpos) * HDIM + tid];
    __syncthreads();

    float scv = -INFINITY;
    if (tid < count) {
        const float* krow = kb + (bh + start + tid) * HDIM;
        float acc = 0.f;
#pragma unroll
        for (int d = 0; d < HDIM; d += 4) {
            float4 kv = *(const float4*)(krow + d);
            acc += kv.x * qs[d] + kv.y * qs[d + 1] + kv.z * qs[d + 2] + kv.w * qs[d + 3];
        }
        scv = acc * 0.08838834764831845f;  // 1/sqrt(128)
    }
    red[tid] = scv;
    __syncthreads();
    for (int off = 128; off > 0; off >>= 1) {
        if (tid < off) red[tid] = fmaxf(red[tid], red[tid + off]);
        __syncthreads();
    }
    const float mmax = red[0];
    __syncthreads();
    float p = (tid < count) ? expf(scv - mmax) : 0.f;
    sc[tid] = p;
    red[tid] = p;
    __syncthreads();
    for (int off = 128; off > 0; off >>= 1) {
        if (tid < off) red[tid] += red[tid + off];
        __syncthreads();
    }
    const float inv = 1.f / red[0];
    if (tid < HDIM) {
        float acc = 0.f;
        const float* vbase = vb + (bh + start) * HDIM + tid;
        for (int j = 0; j < count; ++j)
            acc += sc[j] * vbase[(size_t)j * HDIM];
        ob[(bh + qpos) * HDIM + tid] = acc * inv;
    }
}

// ---------------- GEMM out: C[m,n] = sum_k AO_gathered[m,k] * w_out[n,k] ----------------
// M=4096 N=2048 K=2048; AO gathered from (B,H,S,D).
__global__ __launch_bounds__(256) void gemm_out(const float* __restrict__ AO,
                                                const float* __restrict__ Bm,
                                                float* __restrict__ C) {
    __shared__ float As[BK][64 + 1];
    __shared__ float Bs[BK][64 + 1];
    const int tid = threadIdx.x;
    const int m0 = blockIdx.y * 64;
    const int n0 = blockIdx.x * 64;
    const int lr = tid >> 2;
    const int lc = (tid & 3) * 4;
    const int tx = tid & 15, ty = tid >> 4;
    const int K = EMB;
    float acc[4][4] = {};
    for (int k0 = 0; k0 < K; k0 += BK) {
        int m = m0 + lr;
        int k = k0 + lc;
        // A[m][k] = AO[b][h=k/128][s][d=k%128]
        const float* arow = AO + (((size_t)(m >> 11) * HEADS + (k >> 7)) * S_LEN + (m & 2047)) * HDIM + (k & 127);
        float4 av = *(const float4*)arow;
        float4 bv = *(const float4*)(Bm + (size_t)(n0 + lr) * K + k0 + lc);
        __syncthreads();
        As[lc + 0][lr] = av.x; As[lc + 1][lr] = av.y; As[lc + 2][lr] = av.z; As[lc + 3][lr] = av.w;
        Bs[lc + 0][lr] = bv.x; Bs[lc + 1][lr] = bv.y; Bs[lc + 2][lr] = bv.z; Bs[lc + 3][lr] = bv.w;
        __syncthreads();
#pragma unroll
        for (int kk = 0; kk < BK; ++kk) {
            float a[4], bf[4];
#pragma unroll
            for (int i = 0; i < 4; ++i) a[i] = As[kk][ty * 4 + i];
#pragma unroll
            for (int j = 0; j < 4; ++j) bf[j] = Bs[kk][tx * 4 + j];
#pragma unroll
            for (int i = 0; i < 4; ++i)
#pragma unroll
                for (int j = 0; j < 4; ++j)
                    acc[i][j] = fmaf(a[i], bf[j], acc[i][j]);
        }
    }
#pragma unroll
    for (int i = 0; i < 4; ++i) {
        int m = m0 + ty * 4 + i;
#pragma unroll
        for (int j = 0; j < 4; ++j)
            C[(size_t)m * EMB + n0 + tx * 4 + j] = acc[i][j];
    }
}

// ---------------------------------------------------------------------------
extern "C" void kernel_launch(void* const* d_in, const int* in_sizes, int n_in,
                              void* d_out, int out_size, void* d_ws, size_t ws_size,
                              hipStream_t stream) {
    const float* x     = (const float*)d_in[0];
    const float* w_qkv = (const float*)d_in[1];
    const float* w_out = (const float*)d_in[2];
    const float* w_c1  = (const float*)d_in[3];
    const float* w_c2  = (const float*)d_in[4];
    float* out = (float*)d_out;
    char* ws = (char*)d_ws;

    // ws layout (bytes)
    double* scal  = (double*)(ws + 0);            // sum[2], sumsq[2]
    int*    win   = (int*)(ws + 64);
    float*  xmean = (float*)(ws + 128);           // 2*2048 column sums
    float*  hidden= (float*)(ws + 16640);         // 2*512
    float*  ctab  = (float*)(ws + 32768);         // 1 MB
    float*  stab  = (float*)(ws + 32768 + 1048576);
    float*  qb    = (float*)(ws + (size_t)4 * 1024 * 1024);   // 33.5 MB each
    float*  kb    = qb + (size_t)8388608;
    float*  vb    = kb + (size_t)8388608;
    float*  ao    = vb + (size_t)8388608;

    hipMemsetAsync(d_ws, 0, 32768, stream);       // zero scal + xmean (+ slack)

    rope_table<<<dim3(S_LEN), dim3(HDIM), 0, stream>>>(ctab, stab);
    col_reduce<<<dim3(8, 8, 2), dim3(256), 0, stream>>>(x, xmean, scal);
    hidden_kernel<<<dim3(512, 2), dim3(256), 0, stream>>>(xmean, w_c1, hidden);
    window_kernel<<<dim3(1), dim3(512), 0, stream>>>(hidden, w_c2, scal, win);

    gemm_qkv<<<dim3(96, 64), dim3(256), 0, stream>>>(x, w_qkv, qb, kb, vb);
    rope_apply<<<dim3(16384), dim3(256), 0, stream>>>(qb, kb, ctab, stab);
    attn_kernel<<<dim3(S_LEN, HEADS, 2), dim3(256), 0, stream>>>(qb, kb, vb, ao, win);
    gemm_out<<<dim3(32, 64), dim3(256), 0, stream>>>(ao, w_out, out);
}

// Round 2
// 1358.412 us; speedup vs baseline: 2.7269x; 2.7269x over previous
//
#include <hip/hip_runtime.h>
#include <math.h>

// ---------------------------------------------------------------------------
// AdaptiveWindowAttention — round 2: MFMA f16 GEMMs (m97 structure)
// B=2 S=2048 EMB=2048 H=16 D=128; window in [64,256]
//
//  1. memset ws scalar/xmean area
//  2. rope_table, col_reduce, hidden_kernel, window_kernel  (f64 scalar path)
//  3. cvt_f16: x, w_qkv, w_out -> f16 copies in ws
//  4. gemm_qkv_f16: MFMA 16x16x32_f16, 128x128 tile, global_load_lds staging
//     -> q/k/v f32 in (B,H,S,D)
//  5. rope_apply (f32, in place)
//  6. attn_kernel: one block per (b,h,q); writes ao f16 in (B,S,H*D) row-major
//  7. gemm_out_f16: MFMA, ao16 @ w_out16.T -> d_out f32
// ---------------------------------------------------------------------------

#define S_LEN 2048
#define EMB 2048
#define HEADS 16
#define HDIM 128

typedef _Float16 f16x8 __attribute__((ext_vector_type(8)));
typedef _Float16 f16x4 __attribute__((ext_vector_type(4)));
typedef float f32x4 __attribute__((ext_vector_type(4)));

__device__ __forceinline__ void gld16(const void* g, void* l) {
    __builtin_amdgcn_global_load_lds(
        (const __attribute__((address_space(1))) unsigned int*)g,
        (__attribute__((address_space(3))) unsigned int*)l, 16, 0, 0);
}

// ---------------- rope tables ----------------
__global__ void rope_table(float* __restrict__ ctab, float* __restrict__ stab) {
    int s = blockIdx.x;
    int d = threadIdx.x;
    int j = d & 63;
    double inv = pow(10000.0, -(double)j / 64.0);
    double ang = (double)s * inv;
    ctab[s * HDIM + d] = (float)cos(ang);
    stab[s * HDIM + d] = (float)sin(ang);
}

// ---------------- batch stats ----------------
__global__ __launch_bounds__(256) void col_reduce(const float* __restrict__ x,
                                                  float* __restrict__ xmean_acc,
                                                  double* __restrict__ scal) {
    int b = blockIdx.z;
    int cg = blockIdx.x;
    int sg = blockIdx.y;
    int e = cg * 256 + threadIdx.x;
    const float* xb = x + ((size_t)b * S_LEN + sg * 256) * EMB;
    double csum = 0.0, csq = 0.0;
    for (int s = 0; s < 256; ++s) {
        float v = xb[(size_t)s * EMB + e];
        csum += v;
        csq += (double)v * (double)v;
    }
    atomicAdd(xmean_acc + b * EMB + e, (float)csum);
    __shared__ double rs[256], rq[256];
    rs[threadIdx.x] = csum; rq[threadIdx.x] = csq;
    __syncthreads();
    for (int off = 128; off > 0; off >>= 1) {
        if (threadIdx.x < off) {
            rs[threadIdx.x] += rs[threadIdx.x + off];
            rq[threadIdx.x] += rq[threadIdx.x + off];
        }
        __syncthreads();
    }
    if (threadIdx.x == 0) {
        atomicAdd(&scal[b], rs[0]);
        atomicAdd(&scal[2 + b], rq[0]);
    }
}

__global__ __launch_bounds__(256) void hidden_kernel(const float* __restrict__ xmean_acc,
                                                     const float* __restrict__ wc1,
                                                     float* __restrict__ hidden) {
    int j = blockIdx.x;
    int b = blockIdx.y;
    const float* xm = xmean_acc + b * EMB;
    const float* wr = wc1 + (size_t)j * EMB;
    double acc = 0.0;
    for (int k = threadIdx.x; k < EMB; k += 256)
        acc += (double)xm[k] * (double)wr[k];
    __shared__ double red[256];
    red[threadIdx.x] = acc;
    __syncthreads();
    for (int off = 128; off > 0; off >>= 1) {
        if (threadIdx.x < off) red[threadIdx.x] += red[threadIdx.x + off];
        __syncthreads();
    }
    if (threadIdx.x == 0) {
        double z = red[0] * (1.0 / 2048.0);
        hidden[b * 512 + j] = (float)(z / (1.0 + exp(-z)));
    }
}

__global__ __launch_bounds__(512) void window_kernel(const float* __restrict__ hidden,
                                                     const float* __restrict__ wc2,
                                                     const double* __restrict__ scal,
                                                     int* __restrict__ wout) {
    __shared__ double red[512];
    __shared__ double wfs[2];
    for (int b = 0; b < 2; ++b) {
        red[threadIdx.x] = (double)hidden[b * 512 + threadIdx.x] * (double)wc2[threadIdx.x];
        __syncthreads();
        for (int off = 256; off > 0; off >>= 1) {
            if (threadIdx.x < off) red[threadIdx.x] += red[threadIdx.x + off];
            __syncthreads();
        }
        if (threadIdx.x == 0) {
            double pre = red[0];
            double learned = 1.0 / (1.0 + exp(-pre));
            const double N = (double)S_LEN * (double)EMB;
            double sum = scal[b], sq = scal[2 + b];
            double var = (sq - sum * sum / N) / (N - 1.0);
            double vn = 1.0 / (1.0 + exp(-(var * 10.0 - 5.0)));
            double comp = 0.5 * (vn + learned);
            wfs[b] = 64.0 + comp * 192.0;
        }
        __syncthreads();
    }
    if (threadIdx.x == 0) {
        float wf = (float)(0.5 * (wfs[0] + wfs[1]));
        int w = (int)wf;
        if (w > S_LEN) w = S_LEN;
        if (w < 64) w = 64;
        *wout = w;
    }
}

// ---------------- f32 -> f16 conversion ----------------
__global__ __launch_bounds__(256) void cvt_f16(const float* __restrict__ s,
                                               _Float16* __restrict__ d, int n4) {
    int i = blockIdx.x * 256 + threadIdx.x;
    if (i < n4) {
        float4 v = ((const float4*)s)[i];
        f16x4 o;
        o.x = (_Float16)v.x; o.y = (_Float16)v.y;
        o.z = (_Float16)v.z; o.w = (_Float16)v.w;
        ((f16x4*)d)[i] = o;
    }
}

// ---------------- MFMA GEMM core (m97 structure) ----------------
// C[m,n] = sum_k A[m,k] * W[n,k], A: MxK f16 row-major, W: NxK f16 row-major.
// 128x128 tile, BK=32, 256 threads = 4 waves, each wave 64x64 (4x4 MFMA tiles).
// Epilogue differs between qkv (scatter to q/k/v BHSD) and out (row-major C).

#define GEMM_PROLOGUE(An, Wn)                                                   \
    __shared__ _Float16 As[128 * 32];                                           \
    __shared__ _Float16 Bs[128 * 32];                                           \
    const int tid = threadIdx.x;                                                \
    const int lane = tid & 63;                                                  \
    const int wv = tid >> 6;                                                    \
    const int wm = wv >> 1, wn = wv & 1;                                        \
    const int m0 = blockIdx.y * 128;                                            \
    const int n0 = blockIdx.x * 128;                                            \
    const int srow = wv * 32 + (lane >> 2);                                     \
    const int scol = (lane & 3) * 8;                                            \
    const _Float16* agp = An + (size_t)(m0 + srow) * EMB + scol;                \
    const _Float16* bgp = Wn + (size_t)(n0 + srow) * EMB + scol;                \
    _Float16* al = &As[(wv * 32) * 32];                                         \
    _Float16* bl = &Bs[(wv * 32) * 32];                                         \
    const int frow = lane & 15;                                                 \
    const int fcol = (lane >> 4) * 8;                                           \
    f32x4 acc[4][4] = {};                                                       \
    for (int k0 = 0; k0 < EMB; k0 += 32) {                                      \
        __syncthreads();                                                        \
        gld16(agp, al);                                                         \
        gld16(agp + 16 * EMB, al + 16 * 32);                                    \
        gld16(bgp, bl);                                                         \
        gld16(bgp + 16 * EMB, bl + 16 * 32);                                    \
        agp += 32; bgp += 32;                                                   \
        __syncthreads();                                                        \
        f16x8 af[4], bf[4];                                                     \
        _Pragma("unroll")                                                       \
        for (int i = 0; i < 4; ++i)                                             \
            af[i] = *(const f16x8*)&As[(wm * 64 + i * 16 + frow) * 32 + fcol];  \
        _Pragma("unroll")                                                       \
        for (int j = 0; j < 4; ++j)                                             \
            bf[j] = *(const f16x8*)&Bs[(wn * 64 + j * 16 + frow) * 32 + fcol];  \
        _Pragma("unroll")                                                       \
        for (int i = 0; i < 4; ++i)                                             \
            _Pragma("unroll")                                                   \
            for (int j = 0; j < 4; ++j)                                         \
                acc[i][j] = __builtin_amdgcn_mfma_f32_16x16x32_f16(             \
                    af[i], bf[j], acc[i][j], 0, 0, 0);                          \
    }                                                                           \
    const int colbase = lane & 15;                                              \
    const int rowoff = (lane >> 4) * 4;

__global__ __launch_bounds__(256) void gemm_qkv_f16(const _Float16* __restrict__ An,
                                                    const _Float16* __restrict__ Wn,
                                                    float* __restrict__ qb,
                                                    float* __restrict__ kb,
                                                    float* __restrict__ vb) {
    GEMM_PROLOGUE(An, Wn)
    // n0 is 128-aligned -> whole tile is one (which, head)
    const int which = n0 >> 11;
    const int h = (n0 >> 7) & 15;
    float* dst = which == 0 ? qb : (which == 1 ? kb : vb);
#pragma unroll
    for (int i = 0; i < 4; ++i) {
#pragma unroll
        for (int j = 0; j < 4; ++j) {
            const int d = wn * 64 + j * 16 + colbase;   // 0..127
#pragma unroll
            for (int r = 0; r < 4; ++r) {
                int m = m0 + wm * 64 + i * 16 + rowoff + r;
                int b = m >> 11, s = m & 2047;
                dst[(((size_t)b * HEADS + h) * S_LEN + s) * HDIM + d] = acc[i][j][r];
            }
        }
    }
}

__global__ __launch_bounds__(256) void gemm_out_f16(const _Float16* __restrict__ An,
                                                    const _Float16* __restrict__ Wn,
                                                    float* __restrict__ C) {
    GEMM_PROLOGUE(An, Wn)
#pragma unroll
    for (int i = 0; i < 4; ++i) {
#pragma unroll
        for (int j = 0; j < 4; ++j) {
            const int n = n0 + wn * 64 + j * 16 + colbase;
#pragma unroll
            for (int r = 0; r < 4; ++r) {
                int m = m0 + wm * 64 + i * 16 + rowoff + r;
                C[(size_t)m * EMB + n] = acc[i][j][r];
            }
        }
    }
}

// ---------------- rope in place on q,k ----------------
__global__ __launch_bounds__(256) void rope_apply(float* __restrict__ qb, float* __restrict__ kb,
                                                  const float* __restrict__ ctab,
                                                  const float* __restrict__ stab) {
    size_t idx = (size_t)blockIdx.x * 256 + threadIdx.x;
    int i = idx & 63;
    int s = (int)((idx >> 6) & 2047);
    size_t bh = idx >> 17;
    int d0 = i * 2;
    size_t base = (bh * S_LEN + s) * HDIM + d0;
    float c0 = ctab[s * HDIM + d0], c1 = ctab[s * HDIM + d0 + 1];
    float s0 = stab[s * HDIM + d0], s1 = stab[s * HDIM + d0 + 1];
    float2 q = *(float2*)(qb + base);
    float2 k = *(float2*)(kb + base);
    float2 qn, kn;
    qn.x = q.x * c0 - q.y * s0;  qn.y = q.y * c1 + q.x * s1;
    kn.x = k.x * c0 - k.y * s0;  kn.y = k.y * c1 + k.x * s1;
    *(float2*)(qb + base) = qn;
    *(float2*)(kb + base) = kn;
}

// ---------------- attention: one block per (b,h,q) ----------------
// Writes ao in (B*S, H*D) row-major f16 (GEMM-ready layout).
__global__ __launch_bounds__(256) void attn_kernel(const float* __restrict__ qb,
                                                   const float* __restrict__ kb,
                                                   const float* __restrict__ vb,
                                                   _Float16* __restrict__ ob,
                                                   const int* __restrict__ wptr) {
    const int qpos = blockIdx.x;
    const int h = blockIdx.y;
    const int b = blockIdx.z;
    const int tid = threadIdx.x;
    int window = *wptr;
    if (window > 256) window = 256;
    int start = qpos - window + 1; if (start < 0) start = 0;
    const int count = qpos - start + 1;   // 1..256

    __shared__ float qs[HDIM];
    __shared__ float sc[256];
    __shared__ float red[256];
    const size_t bh = ((size_t)b * HEADS + h) * S_LEN;
    if (tid < HDIM) qs[tid] = qb[(bh + qpos) * HDIM + tid];
    __syncthreads();

    float scv = -INFINITY;
    if (tid < count) {
        const float* krow = kb + (bh + start + tid) * HDIM;
        float acc = 0.f;
#pragma unroll
        for (int d = 0; d < HDIM; d += 4) {
            float4 kv = *(const float4*)(krow + d);
            acc += kv.x * qs[d] + kv.y * qs[d + 1] + kv.z * qs[d + 2] + kv.w * qs[d + 3];
        }
        scv = acc * 0.08838834764831845f;
    }
    red[tid] = scv;
    __syncthreads();
    for (int off = 128; off > 0; off >>= 1) {
        if (tid < off) red[tid] = fmaxf(red[tid], red[tid + off]);
        __syncthreads();
    }
    const float mmax = red[0];
    __syncthreads();
    float p = (tid < count) ? expf(scv - mmax) : 0.f;
    sc[tid] = p;
    red[tid] = p;
    __syncthreads();
    for (int off = 128; off > 0; off >>= 1) {
        if (tid < off) red[tid] += red[tid + off];
        __syncthreads();
    }
    const float inv = 1.f / red[0];
    if (tid < HDIM) {
        float acc = 0.f;
        const float* vbase = vb + (bh + start) * HDIM + tid;
        for (int j = 0; j < count; ++j)
            acc += sc[j] * vbase[(size_t)j * HDIM];
        // ao in (b, s, h, d) row-major
        ob[((size_t)b * S_LEN + qpos) * EMB + h * HDIM + tid] = (_Float16)(acc * inv);
    }
}

// ---------------------------------------------------------------------------
extern "C" void kernel_launch(void* const* d_in, const int* in_sizes, int n_in,
                              void* d_out, int out_size, void* d_ws, size_t ws_size,
                              hipStream_t stream) {
    const float* x     = (const float*)d_in[0];
    const float* w_qkv = (const float*)d_in[1];
    const float* w_out = (const float*)d_in[2];
    const float* w_c1  = (const float*)d_in[3];
    const float* w_c2  = (const float*)d_in[4];
    float* out = (float*)d_out;
    char* ws = (char*)d_ws;

    // ws layout (bytes)
    double*    scal   = (double*)(ws + 0);
    int*       win    = (int*)(ws + 64);
    float*     xmean  = (float*)(ws + 128);
    float*     hidden = (float*)(ws + 16640);
    float*     ctab   = (float*)(ws + 32768);
    float*     stab   = (float*)(ws + 32768 + 1048576);
    float*     qb     = (float*)(ws + 4194304);                 // 33.5 MB
    float*     kb     = (float*)(ws + 37748736);
    float*     vb     = (float*)(ws + 71303168);
    _Float16*  x16    = (_Float16*)(ws + 104857600);            // 16.8 MB (aliases ao16)
    _Float16*  ao16   = (_Float16*)(ws + 104857600);            // alias: x16 dead after gemm_qkv
    _Float16*  wqkv16 = (_Float16*)(ws + 121634816);            // 25.2 MB
    _Float16*  wout16 = (_Float16*)(ws + 146800640);            // 8.4 MB

    hipMemsetAsync(d_ws, 0, 32768, stream);

    rope_table<<<dim3(S_LEN), dim3(HDIM), 0, stream>>>(ctab, stab);
    col_reduce<<<dim3(8, 8, 2), dim3(256), 0, stream>>>(x, xmean, scal);
    hidden_kernel<<<dim3(512, 2), dim3(256), 0, stream>>>(xmean, w_c1, hidden);
    window_kernel<<<dim3(1), dim3(512), 0, stream>>>(hidden, w_c2, scal, win);

    cvt_f16<<<dim3(8192), dim3(256), 0, stream>>>(x, x16, 2097152);       // 2*2048*2048/4
    cvt_f16<<<dim3(12288), dim3(256), 0, stream>>>(w_qkv, wqkv16, 3145728);
    cvt_f16<<<dim3(4096), dim3(256), 0, stream>>>(w_out, wout16, 1048576);

    gemm_qkv_f16<<<dim3(48, 32), dim3(256), 0, stream>>>(x16, wqkv16, qb, kb, vb);
    rope_apply<<<dim3(16384), dim3(256), 0, stream>>>(qb, kb, ctab, stab);
    attn_kernel<<<dim3(S_LEN, HEADS, 2), dim3(256), 0, stream>>>(qb, kb, vb, ao16, win);
    gemm_out_f16<<<dim3(16, 32), dim3(256), 0, stream>>>(ao16, wout16, out);
}

// Round 3
// 477.637 us; speedup vs baseline: 7.7554x; 2.8440x over previous
//
#include <hip/hip_runtime.h>
#include <math.h>

// ---------------------------------------------------------------------------
// AdaptiveWindowAttention — round 3: MFMA attention (flash-style, fixed span)
// B=2 S=2048 EMB=2048 H=16 D=128; window in [64,256]
//
//  1. header kernels (f64 scalar path: var/silu/sigmoid -> window int)
//  2. cvt x16, wqkv16
//  3. gemm_qkv_f16 -> qb,kb f32 (B,H,S,D) + v16t f16 (B,H,D,S)
//  4. rope_apply: qb,kb f32 -> q16,k16 f16 (B,H,S,D)
//  5. attn_mfma: block per (b,h,64q); 320-key span; MFMA QK^T + PV,
//     register softmax w/ shfl_xor, per-wave P through LDS (no barriers)
//  6. cvt wout16; gemm_out_f16 -> d_out f32
// ---------------------------------------------------------------------------

#define S_LEN 2048
#define EMB 2048
#define HEADS 16
#define HDIM 128
#define NT 20          // 320-key span = NT*16
#define PSTR 336       // P row stride in f16 (320 + 16 pad -> conflict-free)

typedef _Float16 f16x8 __attribute__((ext_vector_type(8)));
typedef _Float16 f16x4 __attribute__((ext_vector_type(4)));
typedef _Float16 f16x2 __attribute__((ext_vector_type(2)));
typedef float f32x4 __attribute__((ext_vector_type(4)));

__device__ __forceinline__ void gld16(const void* g, void* l) {
    __builtin_amdgcn_global_load_lds(
        (const __attribute__((address_space(1))) unsigned int*)g,
        (__attribute__((address_space(3))) unsigned int*)l, 16, 0, 0);
}

// ---------------- rope tables ----------------
__global__ void rope_table(float* __restrict__ ctab, float* __restrict__ stab) {
    int s = blockIdx.x;
    int d = threadIdx.x;
    int j = d & 63;
    double inv = pow(10000.0, -(double)j / 64.0);
    double ang = (double)s * inv;
    ctab[s * HDIM + d] = (float)cos(ang);
    stab[s * HDIM + d] = (float)sin(ang);
}

// ---------------- batch stats ----------------
__global__ __launch_bounds__(256) void col_reduce(const float* __restrict__ x,
                                                  float* __restrict__ xmean_acc,
                                                  double* __restrict__ scal) {
    int b = blockIdx.z;
    int cg = blockIdx.x;
    int sg = blockIdx.y;
    int e = cg * 256 + threadIdx.x;
    const float* xb = x + ((size_t)b * S_LEN + sg * 256) * EMB;
    double csum = 0.0, csq = 0.0;
    for (int s = 0; s < 256; ++s) {
        float v = xb[(size_t)s * EMB + e];
        csum += v;
        csq += (double)v * (double)v;
    }
    atomicAdd(xmean_acc + b * EMB + e, (float)csum);
    __shared__ double rs[256], rq[256];
    rs[threadIdx.x] = csum; rq[threadIdx.x] = csq;
    __syncthreads();
    for (int off = 128; off > 0; off >>= 1) {
        if (threadIdx.x < off) {
            rs[threadIdx.x] += rs[threadIdx.x + off];
            rq[threadIdx.x] += rq[threadIdx.x + off];
        }
        __syncthreads();
    }
    if (threadIdx.x == 0) {
        atomicAdd(&scal[b], rs[0]);
        atomicAdd(&scal[2 + b], rq[0]);
    }
}

__global__ __launch_bounds__(256) void hidden_kernel(const float* __restrict__ xmean_acc,
                                                     const float* __restrict__ wc1,
                                                     float* __restrict__ hidden) {
    int j = blockIdx.x;
    int b = blockIdx.y;
    const float* xm = xmean_acc + b * EMB;
    const float* wr = wc1 + (size_t)j * EMB;
    double acc = 0.0;
    for (int k = threadIdx.x; k < EMB; k += 256)
        acc += (double)xm[k] * (double)wr[k];
    __shared__ double red[256];
    red[threadIdx.x] = acc;
    __syncthreads();
    for (int off = 128; off > 0; off >>= 1) {
        if (threadIdx.x < off) red[threadIdx.x] += red[threadIdx.x + off];
        __syncthreads();
    }
    if (threadIdx.x == 0) {
        double z = red[0] * (1.0 / 2048.0);
        hidden[b * 512 + j] = (float)(z / (1.0 + exp(-z)));
    }
}

__global__ __launch_bounds__(512) void window_kernel(const float* __restrict__ hidden,
                                                     const float* __restrict__ wc2,
                                                     const double* __restrict__ scal,
                                                     int* __restrict__ wout) {
    __shared__ double red[512];
    __shared__ double wfs[2];
    for (int b = 0; b < 2; ++b) {
        red[threadIdx.x] = (double)hidden[b * 512 + threadIdx.x] * (double)wc2[threadIdx.x];
        __syncthreads();
        for (int off = 256; off > 0; off >>= 1) {
            if (threadIdx.x < off) red[threadIdx.x] += red[threadIdx.x + off];
            __syncthreads();
        }
        if (threadIdx.x == 0) {
            double pre = red[0];
            double learned = 1.0 / (1.0 + exp(-pre));
            const double N = (double)S_LEN * (double)EMB;
            double sum = scal[b], sq = scal[2 + b];
            double var = (sq - sum * sum / N) / (N - 1.0);
            double vn = 1.0 / (1.0 + exp(-(var * 10.0 - 5.0)));
            double comp = 0.5 * (vn + learned);
            wfs[b] = 64.0 + comp * 192.0;
        }
        __syncthreads();
    }
    if (threadIdx.x == 0) {
        float wf = (float)(0.5 * (wfs[0] + wfs[1]));
        int w = (int)wf;
        if (w > S_LEN) w = S_LEN;
        if (w < 64) w = 64;
        *wout = w;
    }
}

// ---------------- f32 -> f16 conversion ----------------
__global__ __launch_bounds__(256) void cvt_f16(const float* __restrict__ s,
                                               _Float16* __restrict__ d, int n4) {
    int i = blockIdx.x * 256 + threadIdx.x;
    if (i < n4) {
        float4 v = ((const float4*)s)[i];
        f16x4 o;
        o.x = (_Float16)v.x; o.y = (_Float16)v.y;
        o.z = (_Float16)v.z; o.w = (_Float16)v.w;
        ((f16x4*)d)[i] = o;
    }
}

// ---------------- MFMA GEMM core (m97 structure) ----------------
#define GEMM_PROLOGUE(An, Wn)                                                   \
    __shared__ _Float16 As[128 * 32];                                           \
    __shared__ _Float16 Bs[128 * 32];                                           \
    const int tid = threadIdx.x;                                                \
    const int lane = tid & 63;                                                  \
    const int wv = tid >> 6;                                                    \
    const int wm = wv >> 1, wn = wv & 1;                                        \
    const int m0 = blockIdx.y * 128;                                            \
    const int n0 = blockIdx.x * 128;                                            \
    const int srow = wv * 32 + (lane >> 2);                                     \
    const int scol = (lane & 3) * 8;                                            \
    const _Float16* agp = An + (size_t)(m0 + srow) * EMB + scol;                \
    const _Float16* bgp = Wn + (size_t)(n0 + srow) * EMB + scol;                \
    _Float16* al = &As[(wv * 32) * 32];                                         \
    _Float16* bl = &Bs[(wv * 32) * 32];                                         \
    const int frow = lane & 15;                                                 \
    const int fcol = (lane >> 4) * 8;                                           \
    f32x4 acc[4][4] = {};                                                       \
    for (int k0 = 0; k0 < EMB; k0 += 32) {                                      \
        __syncthreads();                                                        \
        gld16(agp, al);                                                         \
        gld16(agp + 16 * EMB, al + 16 * 32);                                    \
        gld16(bgp, bl);                                                         \
        gld16(bgp + 16 * EMB, bl + 16 * 32);                                    \
        agp += 32; bgp += 32;                                                   \
        __syncthreads();                                                        \
        f16x8 af[4], bf[4];                                                     \
        _Pragma("unroll")                                                       \
        for (int i = 0; i < 4; ++i)                                             \
            af[i] = *(const f16x8*)&As[(wm * 64 + i * 16 + frow) * 32 + fcol];  \
        _Pragma("unroll")                                                       \
        for (int j = 0; j < 4; ++j)                                             \
            bf[j] = *(const f16x8*)&Bs[(wn * 64 + j * 16 + frow) * 32 + fcol];  \
        _Pragma("unroll")                                                       \
        for (int i = 0; i < 4; ++i)                                             \
            _Pragma("unroll")                                                   \
            for (int j = 0; j < 4; ++j)                                         \
                acc[i][j] = __builtin_amdgcn_mfma_f32_16x16x32_f16(             \
                    af[i], bf[j], acc[i][j], 0, 0, 0);                          \
    }                                                                           \
    const int colbase = lane & 15;                                              \
    const int rowoff = (lane >> 4) * 4;

// qkv epilogue: q,k -> f32 (B,H,S,D) for rope; v -> f16 transposed (B,H,D,S)
__global__ __launch_bounds__(256) void gemm_qkv_f16(const _Float16* __restrict__ An,
                                                    const _Float16* __restrict__ Wn,
                                                    float* __restrict__ qb,
                                                    float* __restrict__ kb,
                                                    _Float16* __restrict__ vt) {
    GEMM_PROLOGUE(An, Wn)
    const int which = n0 >> 11;
    const int h = (n0 >> 7) & 15;
    if (which == 2) {
#pragma unroll
        for (int i = 0; i < 4; ++i) {
#pragma unroll
            for (int j = 0; j < 4; ++j) {
                const int d = wn * 64 + j * 16 + colbase;
                int m = m0 + wm * 64 + i * 16 + rowoff;  // 4 consecutive rows
                int b = m >> 11, s = m & 2047;
                f16x4 o;
#pragma unroll
                for (int r = 0; r < 4; ++r) o[r] = (_Float16)acc[i][j][r];
                *(f16x4*)&vt[(((size_t)b * HEADS + h) * HDIM + d) * S_LEN + s] = o;
            }
        }
    } else {
        float* dst = which == 0 ? qb : kb;
#pragma unroll
        for (int i = 0; i < 4; ++i) {
#pragma unroll
            for (int j = 0; j < 4; ++j) {
                const int d = wn * 64 + j * 16 + colbase;
#pragma unroll
                for (int r = 0; r < 4; ++r) {
                    int m = m0 + wm * 64 + i * 16 + rowoff + r;
                    int b = m >> 11, s = m & 2047;
                    dst[(((size_t)b * HEADS + h) * S_LEN + s) * HDIM + d] = acc[i][j][r];
                }
            }
        }
    }
}

__global__ __launch_bounds__(256) void gemm_out_f16(const _Float16* __restrict__ An,
                                                    const _Float16* __restrict__ Wn,
                                                    float* __restrict__ C) {
    GEMM_PROLOGUE(An, Wn)
#pragma unroll
    for (int i = 0; i < 4; ++i) {
#pragma unroll
        for (int j = 0; j < 4; ++j) {
            const int n = n0 + wn * 64 + j * 16 + colbase;
#pragma unroll
            for (int r = 0; r < 4; ++r) {
                int m = m0 + wm * 64 + i * 16 + rowoff + r;
                C[(size_t)m * EMB + n] = acc[i][j][r];
            }
        }
    }
}

// ---------------- rope: f32 in -> f16 out ----------------
__global__ __launch_bounds__(256) void rope_apply(const float* __restrict__ qb,
                                                  const float* __restrict__ kb,
                                                  _Float16* __restrict__ q16,
                                                  _Float16* __restrict__ k16,
                                                  const float* __restrict__ ctab,
                                                  const float* __restrict__ stab) {
    size_t idx = (size_t)blockIdx.x * 256 + threadIdx.x;
    int i = idx & 63;
    int s = (int)((idx >> 6) & 2047);
    size_t bh = idx >> 17;
    int d0 = i * 2;
    size_t base = (bh * S_LEN + s) * HDIM + d0;
    float c0 = ctab[s * HDIM + d0], c1 = ctab[s * HDIM + d0 + 1];
    float s0 = stab[s * HDIM + d0], s1 = stab[s * HDIM + d0 + 1];
    float2 q = *(const float2*)(qb + base);
    float2 k = *(const float2*)(kb + base);
    f16x2 qo, ko;
    qo.x = (_Float16)(q.x * c0 - q.y * s0);
    qo.y = (_Float16)(q.y * c1 + q.x * s1);
    ko.x = (_Float16)(k.x * c0 - k.y * s0);
    ko.y = (_Float16)(k.y * c1 + k.x * s1);
    *(f16x2*)(q16 + base) = qo;
    *(f16x2*)(k16 + base) = ko;
}

// ---------------- MFMA attention ----------------
// Block = (64 queries, h, b); 4 waves x 16 queries. Fixed 320-key span
// [q0-256, q0+63]; masking (key>=0, 0<=rel<w) via exp(-inf)=0.
__global__ __launch_bounds__(256) void attn_mfma(const _Float16* __restrict__ q16,
                                                 const _Float16* __restrict__ k16,
                                                 const _Float16* __restrict__ v16t,
                                                 _Float16* __restrict__ ob,
                                                 const int* __restrict__ wptr) {
    const int q0 = blockIdx.x * 64;
    const int h = blockIdx.y;
    const int b = blockIdx.z;
    const int tid = threadIdx.x;
    const int lane = tid & 63;
    const int wv = tid >> 6;
    const int w = *wptr;

    __shared__ _Float16 Pl[4][16 * PSTR];
    _Float16* Pw = Pl[wv];

    const int kstart = q0 - 256;
    int ntlo_w = (257 - w) >> 4;                  // first tile with any rel<w
    int ntlo_n = q0 < 256 ? ((256 - q0) >> 4) : 0; // first tile with key>=0
    const int ntlo = ntlo_w > ntlo_n ? ntlo_w : ntlo_n;

    const int frow = lane & 15;
    const int fgrp = lane >> 4;   // 0..3
    const int fcol = fgrp * 8;

    const size_t bh = (size_t)b * HEADS + h;
    const _Float16* Qp = q16 + (bh * S_LEN + q0 + wv * 16 + frow) * HDIM + fcol;
    const _Float16* Kb = k16 + bh * S_LEN * HDIM;
    const _Float16* Vt = v16t + bh * HDIM * S_LEN;

    // Q A-fragments for the 4 k-steps (reused across all 20 n-tiles)
    f16x8 aq[4];
#pragma unroll
    for (int ks = 0; ks < 4; ++ks) aq[ks] = *(const f16x8*)(Qp + ks * 32);

    // ---- QK^T ----
    f32x4 accs[NT];
#pragma unroll
    for (int nt = 0; nt < NT; ++nt) accs[nt] = (f32x4){0.f, 0.f, 0.f, 0.f};
#pragma unroll
    for (int nt = 0; nt < NT; ++nt) {
        if (nt < ntlo) continue;          // wave-uniform skip of masked tiles
        int krow = kstart + nt * 16 + frow;
        if (krow < 0) krow = 0;           // tile-uniform sign; garbage masked
        const _Float16* kp = Kb + (size_t)krow * HDIM + fcol;
#pragma unroll
        for (int ks = 0; ks < 4; ++ks) {
            f16x8 bk = *(const f16x8*)(kp + ks * 32);
            accs[nt] = __builtin_amdgcn_mfma_f32_16x16x32_f16(aq[ks], bk, accs[nt], 0, 0, 0);
        }
    }

    // ---- mask + scale; row max ----
    const int qrow = fgrp * 4;                // + r
    const int qabs = q0 + wv * 16 + qrow;     // + r
    const float scale = 0.08838834764831845f;
    float mx[4] = {-INFINITY, -INFINITY, -INFINITY, -INFINITY};
#pragma unroll
    for (int nt = 0; nt < NT; ++nt) {
        int key = kstart + nt * 16 + frow;
#pragma unroll
        for (int r = 0; r < 4; ++r) {
            int rel = (qabs + r) - key;
            bool keep = (key >= 0) && (rel >= 0) && (rel < w);
            float s = keep ? accs[nt][r] * scale : -INFINITY;
            accs[nt][r] = s;
            mx[r] = fmaxf(mx[r], s);
        }
    }
#pragma unroll
    for (int r = 0; r < 4; ++r) {
        float m = mx[r];
#pragma unroll
        for (int off = 1; off < 16; off <<= 1)
            m = fmaxf(m, __shfl_xor(m, off, 64));
        mx[r] = m;   // rel==0 always valid -> finite
    }

    // ---- exp, row sum, store P (own wave region; no barrier needed) ----
    float ls[4] = {0.f, 0.f, 0.f, 0.f};
#pragma unroll
    for (int nt = 0; nt < NT; ++nt) {
#pragma unroll
        for (int r = 0; r < 4; ++r) {
            float p = __expf(accs[nt][r] - mx[r]);   // exp(-inf)=0
            ls[r] += p;
            Pw[(qrow + r) * PSTR + nt * 16 + frow] = (_Float16)p;
        }
    }
    float inv[4];
#pragma unroll
    for (int r = 0; r < 4; ++r) {
        float l = ls[r];
#pragma unroll
        for (int off = 1; off < 16; off <<= 1)
            l += __shfl_xor(l, off, 64);
        inv[r] = 1.f / l;
    }

    // ---- PV: O[16q x 128d] = P[16q x 320k] * V^T[128d x 320k]^T ----
    const int pvlo = ntlo >> 1;
    f32x4 acco[8];
#pragma unroll
    for (int jt = 0; jt < 8; ++jt) acco[jt] = (f32x4){0.f, 0.f, 0.f, 0.f};
    const _Float16* Pr = &Pl[wv][frow * PSTR];
#pragma unroll
    for (int kp = 0; kp < 10; ++kp) {
        if (kp < pvlo) continue;
        f16x8 ap = *(const f16x8*)(Pr + kp * 32 + fcol);
        int kv = kstart + kp * 32 + fcol;
        if (kv < 0) kv = 0;               // 8-key chunks share sign; P=0 masks
#pragma unroll
        for (int jt = 0; jt < 8; ++jt) {
            f16x8 bv = *(const f16x8*)(Vt + (size_t)(jt * 16 + frow) * S_LEN + kv);
            acco[jt] = __builtin_amdgcn_mfma_f32_16x16x32_f16(ap, bv, acco[jt], 0, 0, 0);
        }
    }

    // ---- store O (b, s, h*128+d) f16 ----
#pragma unroll
    for (int jt = 0; jt < 8; ++jt) {
#pragma unroll
        for (int r = 0; r < 4; ++r) {
            int s = qabs + r;
            ob[((size_t)b * S_LEN + s) * EMB + h * HDIM + jt * 16 + frow] =
                (_Float16)(acco[jt][r] * inv[r]);
        }
    }
}

// ---------------------------------------------------------------------------
extern "C" void kernel_launch(void* const* d_in, const int* in_sizes, int n_in,
                              void* d_out, int out_size, void* d_ws, size_t ws_size,
                              hipStream_t stream) {
    const float* x     = (const float*)d_in[0];
    const float* w_qkv = (const float*)d_in[1];
    const float* w_out = (const float*)d_in[2];
    const float* w_c1  = (const float*)d_in[3];
    const float* w_c2  = (const float*)d_in[4];
    float* out = (float*)d_out;
    char* ws = (char*)d_ws;

    // ws layout (bytes); aliases exploit liveness:
    //   wqkv16/x16 dead after gemm_qkv -> reused for q16/k16 (rope outputs)
    //   qb dead after rope  -> ao16;  kb dead after rope -> wout16
    double*    scal   = (double*)(ws + 0);
    int*       win    = (int*)(ws + 64);
    float*     xmean  = (float*)(ws + 128);
    float*     hidden = (float*)(ws + 16640);
    float*     ctab   = (float*)(ws + 32768);
    float*     stab   = (float*)(ws + 32768 + 1048576);
    float*     qb     = (float*)(ws + 4194304);     // f32, 33.5 MB
    float*     kb     = (float*)(ws + 37748736);    // f32, 33.5 MB
    _Float16*  wqkv16 = (_Float16*)(ws + 71303168); // 25.2 MB
    _Float16*  x16    = (_Float16*)(ws + 96468992); // 16.8 MB
    _Float16*  v16t   = (_Float16*)(ws + 113246208);// 16.8 MB
    _Float16*  q16    = (_Float16*)(ws + 71303168); // alias wqkv16
    _Float16*  k16    = (_Float16*)(ws + 96468992); // alias x16
    _Float16*  ao16   = (_Float16*)(ws + 4194304);  // alias qb
    _Float16*  wout16 = (_Float16*)(ws + 37748736); // alias kb

    hipMemsetAsync(d_ws, 0, 32768, stream);

    rope_table<<<dim3(S_LEN), dim3(HDIM), 0, stream>>>(ctab, stab);
    col_reduce<<<dim3(8, 8, 2), dim3(256), 0, stream>>>(x, xmean, scal);
    hidden_kernel<<<dim3(512, 2), dim3(256), 0, stream>>>(xmean, w_c1, hidden);
    window_kernel<<<dim3(1), dim3(512), 0, stream>>>(hidden, w_c2, scal, win);

    cvt_f16<<<dim3(8192), dim3(256), 0, stream>>>(x, x16, 2097152);
    cvt_f16<<<dim3(12288), dim3(256), 0, stream>>>(w_qkv, wqkv16, 3145728);

    gemm_qkv_f16<<<dim3(48, 32), dim3(256), 0, stream>>>(x16, wqkv16, qb, kb, v16t);
    rope_apply<<<dim3(16384), dim3(256), 0, stream>>>(qb, kb, q16, k16, ctab, stab);
    attn_mfma<<<dim3(32, HEADS, 2), dim3(256), 0, stream>>>(q16, k16, v16t, ao16, win);

    cvt_f16<<<dim3(4096), dim3(256), 0, stream>>>(w_out, wout16, 1048576);
    gemm_out_f16<<<dim3(16, 32), dim3(256), 0, stream>>>(ao16, wout16, out);
}

// Round 4
// 462.301 us; speedup vs baseline: 8.0126x; 1.0332x over previous
//
#include <hip/hip_runtime.h>
#include <math.h>

// ---------------------------------------------------------------------------
// AdaptiveWindowAttention — round 4: fuse rope into qkv epilogue, cvt into
// col_reduce. B=2 S=2048 EMB=2048 H=16 D=128; window in [64,256]
//
//  1. rope_table -> cstab (float2 cos/sin, 2 MB)
//  2. col_reduce: stats + x -> x16 (fused cvt)
//  3. hidden_kernel, window_kernel (f64 scalar path)
//  4. cvt wqkv16, wout16
//  5. gemm_qkv_f16: MFMA; epilogue applies RoPE via shfl_xor and writes
//     q16/k16 f16 (B,H,S,D) + v16t f16 (B,H,D,S) directly
//  6. attn_mfma: block per (b,h,64q); 320-key span; MFMA QK^T + PV
//  7. gemm_out_f16 -> d_out f32
// ---------------------------------------------------------------------------

#define S_LEN 2048
#define EMB 2048
#define HEADS 16
#define HDIM 128
#define NT 20          // 320-key span = NT*16
#define PSTR 336       // P row stride in f16 (320 + 16 pad -> conflict-free)

typedef _Float16 f16x8 __attribute__((ext_vector_type(8)));
typedef _Float16 f16x4 __attribute__((ext_vector_type(4)));
typedef float f32x4 __attribute__((ext_vector_type(4)));

__device__ __forceinline__ void gld16(const void* g, void* l) {
    __builtin_amdgcn_global_load_lds(
        (const __attribute__((address_space(1))) unsigned int*)g,
        (__attribute__((address_space(3))) unsigned int*)l, 16, 0, 0);
}

// ---------------- rope tables (cos,sin interleaved) ----------------
__global__ void rope_table(float2* __restrict__ cstab) {
    int s = blockIdx.x;
    int d = threadIdx.x;
    int j = d & 63;
    double inv = pow(10000.0, -(double)j / 64.0);
    double ang = (double)s * inv;
    cstab[s * HDIM + d] = make_float2((float)cos(ang), (float)sin(ang));
}

// ---------------- batch stats + fused x->f16 ----------------
__global__ __launch_bounds__(256) void col_reduce(const float* __restrict__ x,
                                                  float* __restrict__ xmean_acc,
                                                  double* __restrict__ scal,
                                                  _Float16* __restrict__ x16) {
    int b = blockIdx.z;
    int cg = blockIdx.x;
    int sg = blockIdx.y;
    int e = cg * 256 + threadIdx.x;
    const size_t base = ((size_t)b * S_LEN + sg * 256) * EMB;
    const float* xb = x + base;
    _Float16* xo = x16 + base;
    double csum = 0.0, csq = 0.0;
    for (int s = 0; s < 256; ++s) {
        float v = xb[(size_t)s * EMB + e];
        xo[(size_t)s * EMB + e] = (_Float16)v;
        csum += v;
        csq += (double)v * (double)v;
    }
    atomicAdd(xmean_acc + b * EMB + e, (float)csum);
    __shared__ double rs[256], rq[256];
    rs[threadIdx.x] = csum; rq[threadIdx.x] = csq;
    __syncthreads();
    for (int off = 128; off > 0; off >>= 1) {
        if (threadIdx.x < off) {
            rs[threadIdx.x] += rs[threadIdx.x + off];
            rq[threadIdx.x] += rq[threadIdx.x + off];
        }
        __syncthreads();
    }
    if (threadIdx.x == 0) {
        atomicAdd(&scal[b], rs[0]);
        atomicAdd(&scal[2 + b], rq[0]);
    }
}

__global__ __launch_bounds__(256) void hidden_kernel(const float* __restrict__ xmean_acc,
                                                     const float* __restrict__ wc1,
                                                     float* __restrict__ hidden) {
    int j = blockIdx.x;
    int b = blockIdx.y;
    const float* xm = xmean_acc + b * EMB;
    const float* wr = wc1 + (size_t)j * EMB;
    double acc = 0.0;
    for (int k = threadIdx.x; k < EMB; k += 256)
        acc += (double)xm[k] * (double)wr[k];
    __shared__ double red[256];
    red[threadIdx.x] = acc;
    __syncthreads();
    for (int off = 128; off > 0; off >>= 1) {
        if (threadIdx.x < off) red[threadIdx.x] += red[threadIdx.x + off];
        __syncthreads();
    }
    if (threadIdx.x == 0) {
        double z = red[0] * (1.0 / 2048.0);
        hidden[b * 512 + j] = (float)(z / (1.0 + exp(-z)));
    }
}

__global__ __launch_bounds__(512) void window_kernel(const float* __restrict__ hidden,
                                                     const float* __restrict__ wc2,
                                                     const double* __restrict__ scal,
                                                     int* __restrict__ wout) {
    __shared__ double red[512];
    __shared__ double wfs[2];
    for (int b = 0; b < 2; ++b) {
        red[threadIdx.x] = (double)hidden[b * 512 + threadIdx.x] * (double)wc2[threadIdx.x];
        __syncthreads();
        for (int off = 256; off > 0; off >>= 1) {
            if (threadIdx.x < off) red[threadIdx.x] += red[threadIdx.x + off];
            __syncthreads();
        }
        if (threadIdx.x == 0) {
            double pre = red[0];
            double learned = 1.0 / (1.0 + exp(-pre));
            const double N = (double)S_LEN * (double)EMB;
            double sum = scal[b], sq = scal[2 + b];
            double var = (sq - sum * sum / N) / (N - 1.0);
            double vn = 1.0 / (1.0 + exp(-(var * 10.0 - 5.0)));
            double comp = 0.5 * (vn + learned);
            wfs[b] = 64.0 + comp * 192.0;
        }
        __syncthreads();
    }
    if (threadIdx.x == 0) {
        float wf = (float)(0.5 * (wfs[0] + wfs[1]));
        int w = (int)wf;
        if (w > S_LEN) w = S_LEN;
        if (w < 64) w = 64;
        *wout = w;
    }
}

// ---------------- f32 -> f16 conversion ----------------
__global__ __launch_bounds__(256) void cvt_f16(const float* __restrict__ s,
                                               _Float16* __restrict__ d, int n4) {
    int i = blockIdx.x * 256 + threadIdx.x;
    if (i < n4) {
        float4 v = ((const float4*)s)[i];
        f16x4 o;
        o.x = (_Float16)v.x; o.y = (_Float16)v.y;
        o.z = (_Float16)v.z; o.w = (_Float16)v.w;
        ((f16x4*)d)[i] = o;
    }
}

// ---------------- MFMA GEMM core (m97 structure) ----------------
#define GEMM_PROLOGUE(An, Wn)                                                   \
    __shared__ _Float16 As[128 * 32];                                           \
    __shared__ _Float16 Bs[128 * 32];                                           \
    const int tid = threadIdx.x;                                                \
    const int lane = tid & 63;                                                  \
    const int wv = tid >> 6;                                                    \
    const int wm = wv >> 1, wn = wv & 1;                                        \
    const int m0 = blockIdx.y * 128;                                            \
    const int n0 = blockIdx.x * 128;                                            \
    const int srow = wv * 32 + (lane >> 2);                                     \
    const int scol = (lane & 3) * 8;                                            \
    const _Float16* agp = An + (size_t)(m0 + srow) * EMB + scol;                \
    const _Float16* bgp = Wn + (size_t)(n0 + srow) * EMB + scol;                \
    _Float16* al = &As[(wv * 32) * 32];                                         \
    _Float16* bl = &Bs[(wv * 32) * 32];                                         \
    const int frow = lane & 15;                                                 \
    const int fcol = (lane >> 4) * 8;                                           \
    f32x4 acc[4][4] = {};                                                       \
    for (int k0 = 0; k0 < EMB; k0 += 32) {                                      \
        __syncthreads();                                                        \
        gld16(agp, al);                                                         \
        gld16(agp + 16 * EMB, al + 16 * 32);                                    \
        gld16(bgp, bl);                                                         \
        gld16(bgp + 16 * EMB, bl + 16 * 32);                                    \
        agp += 32; bgp += 32;                                                   \
        __syncthreads();                                                        \
        f16x8 af[4], bf[4];                                                     \
        _Pragma("unroll")                                                       \
        for (int i = 0; i < 4; ++i)                                             \
            af[i] = *(const f16x8*)&As[(wm * 64 + i * 16 + frow) * 32 + fcol];  \
        _Pragma("unroll")                                                       \
        for (int j = 0; j < 4; ++j)                                             \
            bf[j] = *(const f16x8*)&Bs[(wn * 64 + j * 16 + frow) * 32 + fcol];  \
        _Pragma("unroll")                                                       \
        for (int i = 0; i < 4; ++i)                                             \
            _Pragma("unroll")                                                   \
            for (int j = 0; j < 4; ++j)                                         \
                acc[i][j] = __builtin_amdgcn_mfma_f32_16x16x32_f16(             \
                    af[i], bf[j], acc[i][j], 0, 0, 0);                          \
    }                                                                           \
    const int colbase = lane & 15;                                              \
    const int rowoff = (lane >> 4) * 4;

// qkv epilogue: rope fused -> q16/k16 f16 (B,H,S,D); v -> f16 (B,H,D,S)
__global__ __launch_bounds__(256) void gemm_qkv_f16(const _Float16* __restrict__ An,
                                                    const _Float16* __restrict__ Wn,
                                                    _Float16* __restrict__ q16,
                                                    _Float16* __restrict__ k16,
                                                    _Float16* __restrict__ vt,
                                                    const float2* __restrict__ cstab) {
    GEMM_PROLOGUE(An, Wn)
    const int which = n0 >> 11;
    const int h = (n0 >> 7) & 15;
    if (which == 2) {
#pragma unroll
        for (int i = 0; i < 4; ++i) {
#pragma unroll
            for (int j = 0; j < 4; ++j) {
                const int d = wn * 64 + j * 16 + colbase;
                int m = m0 + wm * 64 + i * 16 + rowoff;  // 4 consecutive rows
                int b = m >> 11, s = m & 2047;
                f16x4 o;
#pragma unroll
                for (int r = 0; r < 4; ++r) o[r] = (_Float16)acc[i][j][r];
                *(f16x4*)&vt[(((size_t)b * HEADS + h) * HDIM + d) * S_LEN + s] = o;
            }
        }
    } else {
        _Float16* dst = which == 0 ? q16 : k16;
        const float sgn = (colbase & 1) ? 1.f : -1.f;   // rotate_half sign
#pragma unroll
        for (int i = 0; i < 4; ++i) {
#pragma unroll
            for (int j = 0; j < 4; ++j) {
                const int d = wn * 64 + j * 16 + colbase;
#pragma unroll
                for (int r = 0; r < 4; ++r) {
                    int m = m0 + wm * 64 + i * 16 + rowoff + r;
                    int b = m >> 11, s = m & 2047;
                    float a = acc[i][j][r];
                    float p = __shfl_xor(a, 1, 64);      // partner: d^1, same s
                    float2 cs = cstab[(size_t)s * HDIM + d];
                    float o = fmaf(a, cs.x, sgn * p * cs.y);
                    dst[(((size_t)b * HEADS + h) * S_LEN + s) * HDIM + d] = (_Float16)o;
                }
            }
        }
    }
}

__global__ __launch_bounds__(256) void gemm_out_f16(const _Float16* __restrict__ An,
                                                    const _Float16* __restrict__ Wn,
                                                    float* __restrict__ C) {
    GEMM_PROLOGUE(An, Wn)
#pragma unroll
    for (int i = 0; i < 4; ++i) {
#pragma unroll
        for (int j = 0; j < 4; ++j) {
            const int n = n0 + wn * 64 + j * 16 + colbase;
#pragma unroll
            for (int r = 0; r < 4; ++r) {
                int m = m0 + wm * 64 + i * 16 + rowoff + r;
                C[(size_t)m * EMB + n] = acc[i][j][r];
            }
        }
    }
}

// ---------------- MFMA attention ----------------
// Block = (64 queries, h, b); 4 waves x 16 queries. Fixed 320-key span
// [q0-256, q0+63]; masking (key>=0, 0<=rel<w) via exp(-inf)=0.
__global__ __launch_bounds__(256) void attn_mfma(const _Float16* __restrict__ q16,
                                                 const _Float16* __restrict__ k16,
                                                 const _Float16* __restrict__ v16t,
                                                 _Float16* __restrict__ ob,
                                                 const int* __restrict__ wptr) {
    const int q0 = blockIdx.x * 64;
    const int h = blockIdx.y;
    const int b = blockIdx.z;
    const int tid = threadIdx.x;
    const int lane = tid & 63;
    const int wv = tid >> 6;
    const int w = *wptr;

    __shared__ _Float16 Pl[4][16 * PSTR];
    _Float16* Pw = Pl[wv];

    const int kstart = q0 - 256;
    int ntlo_w = (257 - w) >> 4;
    int ntlo_n = q0 < 256 ? ((256 - q0) >> 4) : 0;
    const int ntlo = ntlo_w > ntlo_n ? ntlo_w : ntlo_n;

    const int frow = lane & 15;
    const int fgrp = lane >> 4;
    const int fcol = fgrp * 8;

    const size_t bh = (size_t)b * HEADS + h;
    const _Float16* Qp = q16 + (bh * S_LEN + q0 + wv * 16 + frow) * HDIM + fcol;
    const _Float16* Kb = k16 + bh * S_LEN * HDIM;
    const _Float16* Vt = v16t + bh * HDIM * S_LEN;

    f16x8 aq[4];
#pragma unroll
    for (int ks = 0; ks < 4; ++ks) aq[ks] = *(const f16x8*)(Qp + ks * 32);

    // ---- QK^T ----
    f32x4 accs[NT];
#pragma unroll
    for (int nt = 0; nt < NT; ++nt) accs[nt] = (f32x4){0.f, 0.f, 0.f, 0.f};
#pragma unroll
    for (int nt = 0; nt < NT; ++nt) {
        if (nt < ntlo) continue;
        int krow = kstart + nt * 16 + frow;
        if (krow < 0) krow = 0;
        const _Float16* kp = Kb + (size_t)krow * HDIM + fcol;
#pragma unroll
        for (int ks = 0; ks < 4; ++ks) {
            f16x8 bk = *(const f16x8*)(kp + ks * 32);
            accs[nt] = __builtin_amdgcn_mfma_f32_16x16x32_f16(aq[ks], bk, accs[nt], 0, 0, 0);
        }
    }

    // ---- mask + scale; row max ----
    const int qrow = fgrp * 4;
    const int qabs = q0 + wv * 16 + qrow;
    const float scale = 0.08838834764831845f;
    float mx[4] = {-INFINITY, -INFINITY, -INFINITY, -INFINITY};
#pragma unroll
    for (int nt = 0; nt < NT; ++nt) {
        int key = kstart + nt * 16 + frow;
#pragma unroll
        for (int r = 0; r < 4; ++r) {
            int rel = (qabs + r) - key;
            bool keep = (key >= 0) && (rel >= 0) && (rel < w);
            float s = keep ? accs[nt][r] * scale : -INFINITY;
            accs[nt][r] = s;
            mx[r] = fmaxf(mx[r], s);
        }
    }
#pragma unroll
    for (int r = 0; r < 4; ++r) {
        float m = mx[r];
#pragma unroll
        for (int off = 1; off < 16; off <<= 1)
            m = fmaxf(m, __shfl_xor(m, off, 64));
        mx[r] = m;
    }

    // ---- exp, row sum, store P ----
    float ls[4] = {0.f, 0.f, 0.f, 0.f};
#pragma unroll
    for (int nt = 0; nt < NT; ++nt) {
#pragma unroll
        for (int r = 0; r < 4; ++r) {
            float p = __expf(accs[nt][r] - mx[r]);
            ls[r] += p;
            Pw[(qrow + r) * PSTR + nt * 16 + frow] = (_Float16)p;
        }
    }
    float inv[4];
#pragma unroll
    for (int r = 0; r < 4; ++r) {
        float l = ls[r];
#pragma unroll
        for (int off = 1; off < 16; off <<= 1)
            l += __shfl_xor(l, off, 64);
        inv[r] = 1.f / l;
    }

    // ---- PV ----
    const int pvlo = ntlo >> 1;
    f32x4 acco[8];
#pragma unroll
    for (int jt = 0; jt < 8; ++jt) acco[jt] = (f32x4){0.f, 0.f, 0.f, 0.f};
    const _Float16* Pr = &Pl[wv][frow * PSTR];
#pragma unroll
    for (int kp = 0; kp < 10; ++kp) {
        if (kp < pvlo) continue;
        f16x8 ap = *(const f16x8*)(Pr + kp * 32 + fcol);
        int kv = kstart + kp * 32 + fcol;
        if (kv < 0) kv = 0;
#pragma unroll
        for (int jt = 0; jt < 8; ++jt) {
            f16x8 bv = *(const f16x8*)(Vt + (size_t)(jt * 16 + frow) * S_LEN + kv);
            acco[jt] = __builtin_amdgcn_mfma_f32_16x16x32_f16(ap, bv, acco[jt], 0, 0, 0);
        }
    }

    // ---- store O (b, s, h*128+d) f16 ----
#pragma unroll
    for (int jt = 0; jt < 8; ++jt) {
#pragma unroll
        for (int r = 0; r < 4; ++r) {
            int s = qabs + r;
            ob[((size_t)b * S_LEN + s) * EMB + h * HDIM + jt * 16 + frow] =
                (_Float16)(acco[jt][r] * inv[r]);
        }
    }
}

// ---------------------------------------------------------------------------
extern "C" void kernel_launch(void* const* d_in, const int* in_sizes, int n_in,
                              void* d_out, int out_size, void* d_ws, size_t ws_size,
                              hipStream_t stream) {
    const float* x     = (const float*)d_in[0];
    const float* w_qkv = (const float*)d_in[1];
    const float* w_out = (const float*)d_in[2];
    const float* w_c1  = (const float*)d_in[3];
    const float* w_c2  = (const float*)d_in[4];
    float* out = (float*)d_out;
    char* ws = (char*)d_ws;

    // ws layout (bytes). ao16 aliases wqkv16 (dead after gemm_qkv).
    double*    scal   = (double*)(ws + 0);
    int*       win    = (int*)(ws + 64);
    float*     xmean  = (float*)(ws + 128);
    float*     hidden = (float*)(ws + 16640);
    float2*    cstab  = (float2*)(ws + 32768);       // 2 MB
    _Float16*  x16    = (_Float16*)(ws + 4194304);   // 16.8 MB
    _Float16*  wqkv16 = (_Float16*)(ws + 20971520);  // 25.2 MB
    _Float16*  ao16   = (_Float16*)(ws + 20971520);  // alias
    _Float16*  v16t   = (_Float16*)(ws + 46137344);  // 16.8 MB
    _Float16*  q16    = (_Float16*)(ws + 62914560);  // 16.8 MB
    _Float16*  k16    = (_Float16*)(ws + 79691776);  // 16.8 MB
    _Float16*  wout16 = (_Float16*)(ws + 96468992);  // 8.4 MB

    hipMemsetAsync(d_ws, 0, 32768, stream);

    rope_table<<<dim3(S_LEN), dim3(HDIM), 0, stream>>>(cstab);
    col_reduce<<<dim3(8, 8, 2), dim3(256), 0, stream>>>(x, xmean, scal, x16);
    hidden_kernel<<<dim3(512, 2), dim3(256), 0, stream>>>(xmean, w_c1, hidden);
    window_kernel<<<dim3(1), dim3(512), 0, stream>>>(hidden, w_c2, scal, win);

    cvt_f16<<<dim3(12288), dim3(256), 0, stream>>>(w_qkv, wqkv16, 3145728);
    cvt_f16<<<dim3(4096), dim3(256), 0, stream>>>(w_out, wout16, 1048576);

    gemm_qkv_f16<<<dim3(48, 32), dim3(256), 0, stream>>>(x16, wqkv16, q16, k16, v16t, cstab);
    attn_mfma<<<dim3(32, HEADS, 2), dim3(256), 0, stream>>>(q16, k16, v16t, ao16, win);
    gemm_out_f16<<<dim3(16, 32), dim3(256), 0, stream>>>(ao16, wout16, out);
}

// Round 5
// 458.311 us; speedup vs baseline: 8.0824x; 1.0087x over previous
//
#include <hip/hip_runtime.h>
#include <math.h>

// ---------------------------------------------------------------------------
// AdaptiveWindowAttention — round 5: XOR-swizzled LDS in MFMA GEMMs
// (8-way bank conflict -> 2-way == free), col_reduce regrid.
// B=2 S=2048 EMB=2048 H=16 D=128; window in [64,256]
//
// LDS swizzle: LDS(row, chunk) = A[row][chunk ^ ((row>>1)&3)]; staging
// permutes per-lane SOURCE addresses (global_load_lds dest layout is fixed
// lane*16B), fragment reads XOR the chunk back. Bank offsets across the 16
// frow lanes: {0,16,4,20,8,24,12,28} x2 -> 2-way (free) instead of 8-way.
// ---------------------------------------------------------------------------

#define S_LEN 2048
#define EMB 2048
#define HEADS 16
#define HDIM 128
#define NT 20          // 320-key span = NT*16
#define PSTR 336       // P row stride in f16 (320 + 16 pad -> conflict-free)

typedef _Float16 f16x8 __attribute__((ext_vector_type(8)));
typedef _Float16 f16x4 __attribute__((ext_vector_type(4)));
typedef float f32x4 __attribute__((ext_vector_type(4)));

__device__ __forceinline__ void gld16(const void* g, void* l) {
    __builtin_amdgcn_global_load_lds(
        (const __attribute__((address_space(1))) unsigned int*)g,
        (__attribute__((address_space(3))) unsigned int*)l, 16, 0, 0);
}

// ---------------- rope tables (cos,sin interleaved) ----------------
__global__ void rope_table(float2* __restrict__ cstab) {
    int s = blockIdx.x;
    int d = threadIdx.x;
    int j = d & 63;
    double inv = pow(10000.0, -(double)j / 64.0);
    double ang = (double)s * inv;
    cstab[s * HDIM + d] = make_float2((float)cos(ang), (float)sin(ang));
}

// ---------------- batch stats + fused x->f16 ----------------
__global__ __launch_bounds__(256) void col_reduce(const float* __restrict__ x,
                                                  float* __restrict__ xmean_acc,
                                                  double* __restrict__ scal,
                                                  _Float16* __restrict__ x16) {
    int b = blockIdx.z;
    int cg = blockIdx.x;     // 8 column groups
    int sg = blockIdx.y;     // 64 row chunks of 32
    int e = cg * 256 + threadIdx.x;
    const size_t base = ((size_t)b * S_LEN + sg * 32) * EMB;
    const float* xb = x + base;
    _Float16* xo = x16 + base;
    double csum = 0.0, csq = 0.0;
    for (int s = 0; s < 32; ++s) {
        float v = xb[(size_t)s * EMB + e];
        xo[(size_t)s * EMB + e] = (_Float16)v;
        csum += v;
        csq += (double)v * (double)v;
    }
    atomicAdd(xmean_acc + b * EMB + e, (float)csum);
    __shared__ double rs[256], rq[256];
    rs[threadIdx.x] = csum; rq[threadIdx.x] = csq;
    __syncthreads();
    for (int off = 128; off > 0; off >>= 1) {
        if (threadIdx.x < off) {
            rs[threadIdx.x] += rs[threadIdx.x + off];
            rq[threadIdx.x] += rq[threadIdx.x + off];
        }
        __syncthreads();
    }
    if (threadIdx.x == 0) {
        atomicAdd(&scal[b], rs[0]);
        atomicAdd(&scal[2 + b], rq[0]);
    }
}

__global__ __launch_bounds__(256) void hidden_kernel(const float* __restrict__ xmean_acc,
                                                     const float* __restrict__ wc1,
                                                     float* __restrict__ hidden) {
    int j = blockIdx.x;
    int b = blockIdx.y;
    const float* xm = xmean_acc + b * EMB;
    const float* wr = wc1 + (size_t)j * EMB;
    double acc = 0.0;
    for (int k = threadIdx.x; k < EMB; k += 256)
        acc += (double)xm[k] * (double)wr[k];
    __shared__ double red[256];
    red[threadIdx.x] = acc;
    __syncthreads();
    for (int off = 128; off > 0; off >>= 1) {
        if (threadIdx.x < off) red[threadIdx.x] += red[threadIdx.x + off];
        __syncthreads();
    }
    if (threadIdx.x == 0) {
        double z = red[0] * (1.0 / 2048.0);
        hidden[b * 512 + j] = (float)(z / (1.0 + exp(-z)));
    }
}

__global__ __launch_bounds__(512) void window_kernel(const float* __restrict__ hidden,
                                                     const float* __restrict__ wc2,
                                                     const double* __restrict__ scal,
                                                     int* __restrict__ wout) {
    __shared__ double red[512];
    __shared__ double wfs[2];
    for (int b = 0; b < 2; ++b) {
        red[threadIdx.x] = (double)hidden[b * 512 + threadIdx.x] * (double)wc2[threadIdx.x];
        __syncthreads();
        for (int off = 256; off > 0; off >>= 1) {
            if (threadIdx.x < off) red[threadIdx.x] += red[threadIdx.x + off];
            __syncthreads();
        }
        if (threadIdx.x == 0) {
            double pre = red[0];
            double learned = 1.0 / (1.0 + exp(-pre));
            const double N = (double)S_LEN * (double)EMB;
            double sum = scal[b], sq = scal[2 + b];
            double var = (sq - sum * sum / N) / (N - 1.0);
            double vn = 1.0 / (1.0 + exp(-(var * 10.0 - 5.0)));
            double comp = 0.5 * (vn + learned);
            wfs[b] = 64.0 + comp * 192.0;
        }
        __syncthreads();
    }
    if (threadIdx.x == 0) {
        float wf = (float)(0.5 * (wfs[0] + wfs[1]));
        int w = (int)wf;
        if (w > S_LEN) w = S_LEN;
        if (w < 64) w = 64;
        *wout = w;
    }
}

// ---------------- f32 -> f16 conversion ----------------
__global__ __launch_bounds__(256) void cvt_f16(const float* __restrict__ s,
                                               _Float16* __restrict__ d, int n4) {
    int i = blockIdx.x * 256 + threadIdx.x;
    if (i < n4) {
        float4 v = ((const float4*)s)[i];
        f16x4 o;
        o.x = (_Float16)v.x; o.y = (_Float16)v.y;
        o.z = (_Float16)v.z; o.w = (_Float16)v.w;
        ((f16x4*)d)[i] = o;
    }
}

// ---------------- MFMA GEMM core (m97 structure + LDS swizzle) ----------------
#define GEMM_PROLOGUE(An, Wn)                                                   \
    __shared__ _Float16 As[128 * 32];                                           \
    __shared__ _Float16 Bs[128 * 32];                                           \
    const int tid = threadIdx.x;                                                \
    const int lane = tid & 63;                                                  \
    const int wv = tid >> 6;                                                    \
    const int wm = wv >> 1, wn = wv & 1;                                        \
    const int m0 = blockIdx.y * 128;                                            \
    const int n0 = blockIdx.x * 128;                                            \
    const int srow = wv * 32 + (lane >> 2);                                     \
    const int schunk = (lane & 3) ^ ((lane >> 3) & 3);   /* swizzled source */  \
    const int scol = schunk * 8;                                                \
    const _Float16* agp = An + (size_t)(m0 + srow) * EMB + scol;                \
    const _Float16* bgp = Wn + (size_t)(n0 + srow) * EMB + scol;                \
    _Float16* al = &As[(wv * 32) * 32];                                         \
    _Float16* bl = &Bs[(wv * 32) * 32];                                         \
    const int frow = lane & 15;                                                 \
    const int fcol = ((lane >> 4) ^ ((frow >> 1) & 3)) * 8;  /* unswizzle */    \
    f32x4 acc[4][4] = {};                                                       \
    for (int k0 = 0; k0 < EMB; k0 += 32) {                                      \
        __syncthreads();                                                        \
        gld16(agp, al);                                                         \
        gld16(agp + 16 * EMB, al + 16 * 32);                                    \
        gld16(bgp, bl);                                                         \
        gld16(bgp + 16 * EMB, bl + 16 * 32);                                    \
        agp += 32; bgp += 32;                                                   \
        __syncthreads();                                                        \
        f16x8 af[4], bf[4];                                                     \
        _Pragma("unroll")                                                       \
        for (int i = 0; i < 4; ++i)                                             \
            af[i] = *(const f16x8*)&As[(wm * 64 + i * 16 + frow) * 32 + fcol];  \
        _Pragma("unroll")                                                       \
        for (int j = 0; j < 4; ++j)                                             \
            bf[j] = *(const f16x8*)&Bs[(wn * 64 + j * 16 + frow) * 32 + fcol];  \
        _Pragma("unroll")                                                       \
        for (int i = 0; i < 4; ++i)                                             \
            _Pragma("unroll")                                                   \
            for (int j = 0; j < 4; ++j)                                         \
                acc[i][j] = __builtin_amdgcn_mfma_f32_16x16x32_f16(             \
                    af[i], bf[j], acc[i][j], 0, 0, 0);                          \
    }                                                                           \
    const int colbase = lane & 15;                                              \
    const int rowoff = (lane >> 4) * 4;

// qkv epilogue: rope fused -> q16/k16 f16 (B,H,S,D); v -> f16 (B,H,D,S)
__global__ __launch_bounds__(256) void gemm_qkv_f16(const _Float16* __restrict__ An,
                                                    const _Float16* __restrict__ Wn,
                                                    _Float16* __restrict__ q16,
                                                    _Float16* __restrict__ k16,
                                                    _Float16* __restrict__ vt,
                                                    const float2* __restrict__ cstab) {
    GEMM_PROLOGUE(An, Wn)
    const int which = n0 >> 11;
    const int h = (n0 >> 7) & 15;
    if (which == 2) {
#pragma unroll
        for (int i = 0; i < 4; ++i) {
#pragma unroll
            for (int j = 0; j < 4; ++j) {
                const int d = wn * 64 + j * 16 + colbase;
                int m = m0 + wm * 64 + i * 16 + rowoff;  // 4 consecutive rows
                int b = m >> 11, s = m & 2047;
                f16x4 o;
#pragma unroll
                for (int r = 0; r < 4; ++r) o[r] = (_Float16)acc[i][j][r];
                *(f16x4*)&vt[(((size_t)b * HEADS + h) * HDIM + d) * S_LEN + s] = o;
            }
        }
    } else {
        _Float16* dst = which == 0 ? q16 : k16;
        const float sgn = (colbase & 1) ? 1.f : -1.f;   // rotate_half sign
#pragma unroll
        for (int i = 0; i < 4; ++i) {
#pragma unroll
            for (int j = 0; j < 4; ++j) {
                const int d = wn * 64 + j * 16 + colbase;
#pragma unroll
                for (int r = 0; r < 4; ++r) {
                    int m = m0 + wm * 64 + i * 16 + rowoff + r;
                    int b = m >> 11, s = m & 2047;
                    float a = acc[i][j][r];
                    float p = __shfl_xor(a, 1, 64);      // partner: d^1, same s
                    float2 cs = cstab[(size_t)s * HDIM + d];
                    float o = fmaf(a, cs.x, sgn * p * cs.y);
                    dst[(((size_t)b * HEADS + h) * S_LEN + s) * HDIM + d] = (_Float16)o;
                }
            }
        }
    }
}

__global__ __launch_bounds__(256) void gemm_out_f16(const _Float16* __restrict__ An,
                                                    const _Float16* __restrict__ Wn,
                                                    float* __restrict__ C) {
    GEMM_PROLOGUE(An, Wn)
#pragma unroll
    for (int i = 0; i < 4; ++i) {
#pragma unroll
        for (int j = 0; j < 4; ++j) {
            const int n = n0 + wn * 64 + j * 16 + colbase;
#pragma unroll
            for (int r = 0; r < 4; ++r) {
                int m = m0 + wm * 64 + i * 16 + rowoff + r;
                C[(size_t)m * EMB + n] = acc[i][j][r];
            }
        }
    }
}

// ---------------- MFMA attention ----------------
__global__ __launch_bounds__(256) void attn_mfma(const _Float16* __restrict__ q16,
                                                 const _Float16* __restrict__ k16,
                                                 const _Float16* __restrict__ v16t,
                                                 _Float16* __restrict__ ob,
                                                 const int* __restrict__ wptr) {
    const int q0 = blockIdx.x * 64;
    const int h = blockIdx.y;
    const int b = blockIdx.z;
    const int tid = threadIdx.x;
    const int lane = tid & 63;
    const int wv = tid >> 6;
    const int w = *wptr;

    __shared__ _Float16 Pl[4][16 * PSTR];
    _Float16* Pw = Pl[wv];

    const int kstart = q0 - 256;
    int ntlo_w = (257 - w) >> 4;
    int ntlo_n = q0 < 256 ? ((256 - q0) >> 4) : 0;
    const int ntlo = ntlo_w > ntlo_n ? ntlo_w : ntlo_n;

    const int frow = lane & 15;
    const int fgrp = lane >> 4;
    const int fcol = fgrp * 8;

    const size_t bh = (size_t)b * HEADS + h;
    const _Float16* Qp = q16 + (bh * S_LEN + q0 + wv * 16 + frow) * HDIM + fcol;
    const _Float16* Kb = k16 + bh * S_LEN * HDIM;
    const _Float16* Vt = v16t + bh * HDIM * S_LEN;

    f16x8 aq[4];
#pragma unroll
    for (int ks = 0; ks < 4; ++ks) aq[ks] = *(const f16x8*)(Qp + ks * 32);

    // ---- QK^T ----
    f32x4 accs[NT];
#pragma unroll
    for (int nt = 0; nt < NT; ++nt) accs[nt] = (f32x4){0.f, 0.f, 0.f, 0.f};
#pragma unroll
    for (int nt = 0; nt < NT; ++nt) {
        if (nt < ntlo) continue;
        int krow = kstart + nt * 16 + frow;
        if (krow < 0) krow = 0;
        const _Float16* kp = Kb + (size_t)krow * HDIM + fcol;
#pragma unroll
        for (int ks = 0; ks < 4; ++ks) {
            f16x8 bk = *(const f16x8*)(kp + ks * 32);
            accs[nt] = __builtin_amdgcn_mfma_f32_16x16x32_f16(aq[ks], bk, accs[nt], 0, 0, 0);
        }
    }

    // ---- mask + scale; row max ----
    const int qrow = fgrp * 4;
    const int qabs = q0 + wv * 16 + qrow;
    const float scale = 0.08838834764831845f;
    float mx[4] = {-INFINITY, -INFINITY, -INFINITY, -INFINITY};
#pragma unroll
    for (int nt = 0; nt < NT; ++nt) {
        int key = kstart + nt * 16 + frow;
#pragma unroll
        for (int r = 0; r < 4; ++r) {
            int rel = (qabs + r) - key;
            bool keep = (key >= 0) && (rel >= 0) && (rel < w);
            float s = keep ? accs[nt][r] * scale : -INFINITY;
            accs[nt][r] = s;
            mx[r] = fmaxf(mx[r], s);
        }
    }
#pragma unroll
    for (int r = 0; r < 4; ++r) {
        float m = mx[r];
#pragma unroll
        for (int off = 1; off < 16; off <<= 1)
            m = fmaxf(m, __shfl_xor(m, off, 64));
        mx[r] = m;
    }

    // ---- exp, row sum, store P ----
    float ls[4] = {0.f, 0.f, 0.f, 0.f};
#pragma unroll
    for (int nt = 0; nt < NT; ++nt) {
#pragma unroll
        for (int r = 0; r < 4; ++r) {
            float p = __expf(accs[nt][r] - mx[r]);
            ls[r] += p;
            Pw[(qrow + r) * PSTR + nt * 16 + frow] = (_Float16)p;
        }
    }
    float inv[4];
#pragma unroll
    for (int r = 0; r < 4; ++r) {
        float l = ls[r];
#pragma unroll
        for (int off = 1; off < 16; off <<= 1)
            l += __shfl_xor(l, off, 64);
        inv[r] = 1.f / l;
    }

    // ---- PV ----
    const int pvlo = ntlo >> 1;
    f32x4 acco[8];
#pragma unroll
    for (int jt = 0; jt < 8; ++jt) acco[jt] = (f32x4){0.f, 0.f, 0.f, 0.f};
    const _Float16* Pr = &Pl[wv][frow * PSTR];
#pragma unroll
    for (int kp = 0; kp < 10; ++kp) {
        if (kp < pvlo) continue;
        f16x8 ap = *(const f16x8*)(Pr + kp * 32 + fcol);
        int kv = kstart + kp * 32 + fcol;
        if (kv < 0) kv = 0;
#pragma unroll
        for (int jt = 0; jt < 8; ++jt) {
            f16x8 bv = *(const f16x8*)(Vt + (size_t)(jt * 16 + frow) * S_LEN + kv);
            acco[jt] = __builtin_amdgcn_mfma_f32_16x16x32_f16(ap, bv, acco[jt], 0, 0, 0);
        }
    }

    // ---- store O (b, s, h*128+d) f16 ----
#pragma unroll
    for (int jt = 0; jt < 8; ++jt) {
#pragma unroll
        for (int r = 0; r < 4; ++r) {
            int s = qabs + r;
            ob[((size_t)b * S_LEN + s) * EMB + h * HDIM + jt * 16 + frow] =
                (_Float16)(acco[jt][r] * inv[r]);
        }
    }
}

// ---------------------------------------------------------------------------
extern "C" void kernel_launch(void* const* d_in, const int* in_sizes, int n_in,
                              void* d_out, int out_size, void* d_ws, size_t ws_size,
                              hipStream_t stream) {
    const float* x     = (const float*)d_in[0];
    const float* w_qkv = (const float*)d_in[1];
    const float* w_out = (const float*)d_in[2];
    const float* w_c1  = (const float*)d_in[3];
    const float* w_c2  = (const float*)d_in[4];
    float* out = (float*)d_out;
    char* ws = (char*)d_ws;

    // ws layout (bytes). ao16 aliases wqkv16 (dead after gemm_qkv).
    double*    scal   = (double*)(ws + 0);
    int*       win    = (int*)(ws + 64);
    float*     xmean  = (float*)(ws + 128);
    float*     hidden = (float*)(ws + 16640);
    float2*    cstab  = (float2*)(ws + 32768);       // 2 MB
    _Float16*  x16    = (_Float16*)(ws + 4194304);   // 16.8 MB
    _Float16*  wqkv16 = (_Float16*)(ws + 20971520);  // 25.2 MB
    _Float16*  ao16   = (_Float16*)(ws + 20971520);  // alias
    _Float16*  v16t   = (_Float16*)(ws + 46137344);  // 16.8 MB
    _Float16*  q16    = (_Float16*)(ws + 62914560);  // 16.8 MB
    _Float16*  k16    = (_Float16*)(ws + 79691776);  // 16.8 MB
    _Float16*  wout16 = (_Float16*)(ws + 96468992);  // 8.4 MB

    hipMemsetAsync(d_ws, 0, 32768, stream);

    rope_table<<<dim3(S_LEN), dim3(HDIM), 0, stream>>>(cstab);
    col_reduce<<<dim3(8, 64, 2), dim3(256), 0, stream>>>(x, xmean, scal, x16);
    hidden_kernel<<<dim3(512, 2), dim3(256), 0, stream>>>(xmean, w_c1, hidden);
    window_kernel<<<dim3(1), dim3(512), 0, stream>>>(hidden, w_c2, scal, win);

    cvt_f16<<<dim3(12288), dim3(256), 0, stream>>>(w_qkv, wqkv16, 3145728);
    cvt_f16<<<dim3(4096), dim3(256), 0, stream>>>(w_out, wout16, 1048576);

    gemm_qkv_f16<<<dim3(48, 32), dim3(256), 0, stream>>>(x16, wqkv16, q16, k16, v16t, cstab);
    attn_mfma<<<dim3(32, HEADS, 2), dim3(256), 0, stream>>>(q16, k16, v16t, ao16, win);
    gemm_out_f16<<<dim3(16, 32), dim3(256), 0, stream>>>(ao16, wout16, out);
}

// Round 6
// 406.374 us; speedup vs baseline: 9.1154x; 1.1278x over previous
//
#include <hip/hip_runtime.h>
#include <math.h>

// ---------------------------------------------------------------------------
// AdaptiveWindowAttention — round 6: BK=64 GEMMs (half the barrier drains),
// xor-swizzled 64-col LDS rows, float4 col_reduce, merged weight cvt.
// B=2 S=2048 EMB=2048 H=16 D=128; window in [64,256]
//
// LDS swizzle (BK=64, 8 chunks/row): LDS(row, p) = A[row][p ^ (row&7)].
// Staging source chunk = (lane&7) ^ ((lane>>3)&7) (dest is fixed lane*16B);
// fragment read chunk = (ks*4 + fgrp) ^ (frow&7). Whole-wave ds_read_b128:
// 2 lanes/bank everywhere -> free (m136).
// ---------------------------------------------------------------------------

#define S_LEN 2048
#define EMB 2048
#define HEADS 16
#define HDIM 128
#define NT 20          // 320-key span = NT*16
#define PSTR 336       // P row stride in f16 (320 + 16 pad -> conflict-free)

typedef _Float16 f16x8 __attribute__((ext_vector_type(8)));
typedef _Float16 f16x4 __attribute__((ext_vector_type(4)));
typedef float f32x4 __attribute__((ext_vector_type(4)));

__device__ __forceinline__ void gld16(const void* g, void* l) {
    __builtin_amdgcn_global_load_lds(
        (const __attribute__((address_space(1))) unsigned int*)g,
        (__attribute__((address_space(3))) unsigned int*)l, 16, 0, 0);
}

// ---------------- rope tables (cos,sin interleaved) ----------------
__global__ void rope_table(float2* __restrict__ cstab) {
    int s = blockIdx.x;
    int d = threadIdx.x;
    int j = d & 63;
    double inv = pow(10000.0, -(double)j / 64.0);
    double ang = (double)s * inv;
    cstab[s * HDIM + d] = make_float2((float)cos(ang), (float)sin(ang));
}

// ---------------- batch stats + fused x->f16 (float4, 4 cols/thread) --------
__global__ __launch_bounds__(256) void col_reduce(const float* __restrict__ x,
                                                  float* __restrict__ xmean_acc,
                                                  double* __restrict__ scal,
                                                  _Float16* __restrict__ x16) {
    int b = blockIdx.z;
    int cg = blockIdx.x;     // 2 column groups of 1024
    int sg = blockIdx.y;     // 64 row chunks of 32
    int e4 = cg * 256 + threadIdx.x;          // float4 column index
    const size_t base = ((size_t)b * S_LEN + sg * 32) * EMB;
    const float4* xb = (const float4*)(x + base) + e4;
    f16x4* xo = (f16x4*)(x16 + base) + e4;
    double cs0 = 0.0, cs1 = 0.0, cs2 = 0.0, cs3 = 0.0;
    double cq = 0.0;
    for (int s = 0; s < 32; ++s) {
        float4 v = xb[(size_t)s * (EMB / 4)];
        f16x4 o;
        o.x = (_Float16)v.x; o.y = (_Float16)v.y;
        o.z = (_Float16)v.z; o.w = (_Float16)v.w;
        xo[(size_t)s * (EMB / 4)] = o;
        cs0 += v.x; cs1 += v.y; cs2 += v.z; cs3 += v.w;
        cq += (double)v.x * v.x + (double)v.y * v.y +
              (double)v.z * v.z + (double)v.w * v.w;
    }
    float* xm = xmean_acc + b * EMB + e4 * 4;
    atomicAdd(xm + 0, (float)cs0);
    atomicAdd(xm + 1, (float)cs1);
    atomicAdd(xm + 2, (float)cs2);
    atomicAdd(xm + 3, (float)cs3);
    __shared__ double rs[256], rq[256];
    rs[threadIdx.x] = cs0 + cs1 + cs2 + cs3;
    rq[threadIdx.x] = cq;
    __syncthreads();
    for (int off = 128; off > 0; off >>= 1) {
        if (threadIdx.x < off) {
            rs[threadIdx.x] += rs[threadIdx.x + off];
            rq[threadIdx.x] += rq[threadIdx.x + off];
        }
        __syncthreads();
    }
    if (threadIdx.x == 0) {
        atomicAdd(&scal[b], rs[0]);
        atomicAdd(&scal[2 + b], rq[0]);
    }
}

__global__ __launch_bounds__(256) void hidden_kernel(const float* __restrict__ xmean_acc,
                                                     const float* __restrict__ wc1,
                                                     float* __restrict__ hidden) {
    int j = blockIdx.x;
    int b = blockIdx.y;
    const float* xm = xmean_acc + b * EMB;
    const float* wr = wc1 + (size_t)j * EMB;
    double acc = 0.0;
    for (int k = threadIdx.x; k < EMB; k += 256)
        acc += (double)xm[k] * (double)wr[k];
    __shared__ double red[256];
    red[threadIdx.x] = acc;
    __syncthreads();
    for (int off = 128; off > 0; off >>= 1) {
        if (threadIdx.x < off) red[threadIdx.x] += red[threadIdx.x + off];
        __syncthreads();
    }
    if (threadIdx.x == 0) {
        double z = red[0] * (1.0 / 2048.0);
        hidden[b * 512 + j] = (float)(z / (1.0 + exp(-z)));
    }
}

__global__ __launch_bounds__(512) void window_kernel(const float* __restrict__ hidden,
                                                     const float* __restrict__ wc2,
                                                     const double* __restrict__ scal,
                                                     int* __restrict__ wout) {
    __shared__ double red[512];
    __shared__ double wfs[2];
    for (int b = 0; b < 2; ++b) {
        red[threadIdx.x] = (double)hidden[b * 512 + threadIdx.x] * (double)wc2[threadIdx.x];
        __syncthreads();
        for (int off = 256; off > 0; off >>= 1) {
            if (threadIdx.x < off) red[threadIdx.x] += red[threadIdx.x + off];
            __syncthreads();
        }
        if (threadIdx.x == 0) {
            double pre = red[0];
            double learned = 1.0 / (1.0 + exp(-pre));
            const double N = (double)S_LEN * (double)EMB;
            double sum = scal[b], sq = scal[2 + b];
            double var = (sq - sum * sum / N) / (N - 1.0);
            double vn = 1.0 / (1.0 + exp(-(var * 10.0 - 5.0)));
            double comp = 0.5 * (vn + learned);
            wfs[b] = 64.0 + comp * 192.0;
        }
        __syncthreads();
    }
    if (threadIdx.x == 0) {
        float wf = (float)(0.5 * (wfs[0] + wfs[1]));
        int w = (int)wf;
        if (w > S_LEN) w = S_LEN;
        if (w < 64) w = 64;
        *wout = w;
    }
}

// ---------------- f32 -> f16 conversion (both weights, one launch) ----------
#define NQKV4 3145728   // 3*2048*2048/4
#define NOUT4 1048576   // 2048*2048/4
__global__ __launch_bounds__(256) void cvt_weights(const float* __restrict__ wqkv,
                                                   const float* __restrict__ wout,
                                                   _Float16* __restrict__ d_qkv,
                                                   _Float16* __restrict__ d_out) {
    int i = blockIdx.x * 256 + threadIdx.x;
    const float4* s;
    f16x4* d;
    if (i < NQKV4) {
        s = (const float4*)wqkv + i;
        d = (f16x4*)d_qkv + i;
    } else {
        s = (const float4*)wout + (i - NQKV4);
        d = (f16x4*)d_out + (i - NQKV4);
    }
    float4 v = *s;
    f16x4 o;
    o.x = (_Float16)v.x; o.y = (_Float16)v.y;
    o.z = (_Float16)v.z; o.w = (_Float16)v.w;
    *d = o;
}

// ---------------- MFMA GEMM core (BK=64, swizzled LDS) ----------------
#define GEMM_PROLOGUE(An, Wn)                                                   \
    __shared__ _Float16 As[128 * 64];                                           \
    __shared__ _Float16 Bs[128 * 64];                                           \
    const int tid = threadIdx.x;                                                \
    const int lane = tid & 63;                                                  \
    const int wv = tid >> 6;                                                    \
    const int wm = wv >> 1, wn = wv & 1;                                        \
    const int m0 = blockIdx.y * 128;                                            \
    const int n0 = blockIdx.x * 128;                                            \
    const int lrow = lane >> 3;                            /* 0..7 */           \
    const int lchk = (lane & 7) ^ lrow;                    /* swizzled src */   \
    const int srow = wv * 32 + lrow;                                            \
    const _Float16* agp = An + (size_t)(m0 + srow) * EMB + lchk * 8;            \
    const _Float16* bgp = Wn + (size_t)(n0 + srow) * EMB + lchk * 8;            \
    _Float16* al = &As[wv * 32 * 64];                                           \
    _Float16* bl = &Bs[wv * 32 * 64];                                           \
    const int frow = lane & 15;                                                 \
    const int fgrp = lane >> 4;                                                 \
    f32x4 acc[4][4] = {};                                                       \
    for (int k0 = 0; k0 < EMB; k0 += 64) {                                      \
        __syncthreads();                                                        \
        _Pragma("unroll")                                                       \
        for (int t = 0; t < 4; ++t) {                                           \
            gld16(agp + (size_t)t * 8 * EMB, al + t * 8 * 64);                  \
            gld16(bgp + (size_t)t * 8 * EMB, bl + t * 8 * 64);                  \
        }                                                                       \
        agp += 64; bgp += 64;                                                   \
        __syncthreads();                                                        \
        _Pragma("unroll")                                                       \
        for (int ks = 0; ks < 2; ++ks) {                                        \
            f16x8 af[4], bf[4];                                                 \
            _Pragma("unroll")                                                   \
            for (int i = 0; i < 4; ++i)                                         \
                af[i] = *(const f16x8*)&As[(wm * 64 + i * 16 + frow) * 64 +     \
                                           (((ks * 4 + fgrp) ^ (frow & 7)) * 8)]; \
            _Pragma("unroll")                                                   \
            for (int j = 0; j < 4; ++j)                                         \
                bf[j] = *(const f16x8*)&Bs[(wn * 64 + j * 16 + frow) * 64 +     \
                                           (((ks * 4 + fgrp) ^ (frow & 7)) * 8)]; \
            _Pragma("unroll")                                                   \
            for (int i = 0; i < 4; ++i)                                         \
                _Pragma("unroll")                                               \
                for (int j = 0; j < 4; ++j)                                     \
                    acc[i][j] = __builtin_amdgcn_mfma_f32_16x16x32_f16(         \
                        af[i], bf[j], acc[i][j], 0, 0, 0);                      \
        }                                                                       \
    }                                                                           \
    const int colbase = lane & 15;                                              \
    const int rowoff = (lane >> 4) * 4;

// qkv epilogue: rope fused -> q16/k16 f16 (B,H,S,D); v -> f16 (B,H,D,S)
__global__ __launch_bounds__(256) void gemm_qkv_f16(const _Float16* __restrict__ An,
                                                    const _Float16* __restrict__ Wn,
                                                    _Float16* __restrict__ q16,
                                                    _Float16* __restrict__ k16,
                                                    _Float16* __restrict__ vt,
                                                    const float2* __restrict__ cstab) {
    GEMM_PROLOGUE(An, Wn)
    const int which = n0 >> 11;
    const int h = (n0 >> 7) & 15;
    if (which == 2) {
#pragma unroll
        for (int i = 0; i < 4; ++i) {
#pragma unroll
            for (int j = 0; j < 4; ++j) {
                const int d = wn * 64 + j * 16 + colbase;
                int m = m0 + wm * 64 + i * 16 + rowoff;  // 4 consecutive rows
                int b = m >> 11, s = m & 2047;
                f16x4 o;
#pragma unroll
                for (int r = 0; r < 4; ++r) o[r] = (_Float16)acc[i][j][r];
                *(f16x4*)&vt[(((size_t)b * HEADS + h) * HDIM + d) * S_LEN + s] = o;
            }
        }
    } else {
        _Float16* dst = which == 0 ? q16 : k16;
        const float sgn = (colbase & 1) ? 1.f : -1.f;   // rotate_half sign
#pragma unroll
        for (int i = 0; i < 4; ++i) {
#pragma unroll
            for (int j = 0; j < 4; ++j) {
                const int d = wn * 64 + j * 16 + colbase;
#pragma unroll
                for (int r = 0; r < 4; ++r) {
                    int m = m0 + wm * 64 + i * 16 + rowoff + r;
                    int b = m >> 11, s = m & 2047;
                    float a = acc[i][j][r];
                    float p = __shfl_xor(a, 1, 64);      // partner: d^1, same s
                    float2 cs = cstab[(size_t)s * HDIM + d];
                    float o = fmaf(a, cs.x, sgn * p * cs.y);
                    dst[(((size_t)b * HEADS + h) * S_LEN + s) * HDIM + d] = (_Float16)o;
                }
            }
        }
    }
}

__global__ __launch_bounds__(256) void gemm_out_f16(const _Float16* __restrict__ An,
                                                    const _Float16* __restrict__ Wn,
                                                    float* __restrict__ C) {
    GEMM_PROLOGUE(An, Wn)
#pragma unroll
    for (int i = 0; i < 4; ++i) {
#pragma unroll
        for (int j = 0; j < 4; ++j) {
            const int n = n0 + wn * 64 + j * 16 + colbase;
#pragma unroll
            for (int r = 0; r < 4; ++r) {
                int m = m0 + wm * 64 + i * 16 + rowoff + r;
                C[(size_t)m * EMB + n] = acc[i][j][r];
            }
        }
    }
}

// ---------------- MFMA attention ----------------
__global__ __launch_bounds__(256) void attn_mfma(const _Float16* __restrict__ q16,
                                                 const _Float16* __restrict__ k16,
                                                 const _Float16* __restrict__ v16t,
                                                 _Float16* __restrict__ ob,
                                                 const int* __restrict__ wptr) {
    const int q0 = blockIdx.x * 64;
    const int h = blockIdx.y;
    const int b = blockIdx.z;
    const int tid = threadIdx.x;
    const int lane = tid & 63;
    const int wv = tid >> 6;
    const int w = *wptr;

    __shared__ _Float16 Pl[4][16 * PSTR];
    _Float16* Pw = Pl[wv];

    const int kstart = q0 - 256;
    int ntlo_w = (257 - w) >> 4;
    int ntlo_n = q0 < 256 ? ((256 - q0) >> 4) : 0;
    const int ntlo = ntlo_w > ntlo_n ? ntlo_w : ntlo_n;

    const int frow = lane & 15;
    const int fgrp = lane >> 4;
    const int fcol = fgrp * 8;

    const size_t bh = (size_t)b * HEADS + h;
    const _Float16* Qp = q16 + (bh * S_LEN + q0 + wv * 16 + frow) * HDIM + fcol;
    const _Float16* Kb = k16 + bh * S_LEN * HDIM;
    const _Float16* Vt = v16t + bh * HDIM * S_LEN;

    f16x8 aq[4];
#pragma unroll
    for (int ks = 0; ks < 4; ++ks) aq[ks] = *(const f16x8*)(Qp + ks * 32);

    // ---- QK^T ----
    f32x4 accs[NT];
#pragma unroll
    for (int nt = 0; nt < NT; ++nt) accs[nt] = (f32x4){0.f, 0.f, 0.f, 0.f};
#pragma unroll
    for (int nt = 0; nt < NT; ++nt) {
        if (nt < ntlo) continue;
        int krow = kstart + nt * 16 + frow;
        if (krow < 0) krow = 0;
        const _Float16* kp = Kb + (size_t)krow * HDIM + fcol;
#pragma unroll
        for (int ks = 0; ks < 4; ++ks) {
            f16x8 bk = *(const f16x8*)(kp + ks * 32);
            accs[nt] = __builtin_amdgcn_mfma_f32_16x16x32_f16(aq[ks], bk, accs[nt], 0, 0, 0);
        }
    }

    // ---- mask + scale; row max ----
    const int qrow = fgrp * 4;
    const int qabs = q0 + wv * 16 + qrow;
    const float scale = 0.08838834764831845f;
    float mx[4] = {-INFINITY, -INFINITY, -INFINITY, -INFINITY};
#pragma unroll
    for (int nt = 0; nt < NT; ++nt) {
        int key = kstart + nt * 16 + frow;
#pragma unroll
        for (int r = 0; r < 4; ++r) {
            int rel = (qabs + r) - key;
            bool keep = (key >= 0) && (rel >= 0) && (rel < w);
            float s = keep ? accs[nt][r] * scale : -INFINITY;
            accs[nt][r] = s;
            mx[r] = fmaxf(mx[r], s);
        }
    }
#pragma unroll
    for (int r = 0; r < 4; ++r) {
        float m = mx[r];
#pragma unroll
        for (int off = 1; off < 16; off <<= 1)
            m = fmaxf(m, __shfl_xor(m, off, 64));
        mx[r] = m;
    }

    // ---- exp, row sum, store P ----
    float ls[4] = {0.f, 0.f, 0.f, 0.f};
#pragma unroll
    for (int nt = 0; nt < NT; ++nt) {
#pragma unroll
        for (int r = 0; r < 4; ++r) {
            float p = __expf(accs[nt][r] - mx[r]);
            ls[r] += p;
            Pw[(qrow + r) * PSTR + nt * 16 + frow] = (_Float16)p;
        }
    }
    float inv[4];
#pragma unroll
    for (int r = 0; r < 4; ++r) {
        float l = ls[r];
#pragma unroll
        for (int off = 1; off < 16; off <<= 1)
            l += __shfl_xor(l, off, 64);
        inv[r] = 1.f / l;
    }

    // ---- PV ----
    const int pvlo = ntlo >> 1;
    f32x4 acco[8];
#pragma unroll
    for (int jt = 0; jt < 8; ++jt) acco[jt] = (f32x4){0.f, 0.f, 0.f, 0.f};
    const _Float16* Pr = &Pl[wv][frow * PSTR];
#pragma unroll
    for (int kp = 0; kp < 10; ++kp) {
        if (kp < pvlo) continue;
        f16x8 ap = *(const f16x8*)(Pr + kp * 32 + fcol);
        int kv = kstart + kp * 32 + fcol;
        if (kv < 0) kv = 0;
#pragma unroll
        for (int jt = 0; jt < 8; ++jt) {
            f16x8 bv = *(const f16x8*)(Vt + (size_t)(jt * 16 + frow) * S_LEN + kv);
            acco[jt] = __builtin_amdgcn_mfma_f32_16x16x32_f16(ap, bv, acco[jt], 0, 0, 0);
        }
    }

    // ---- store O (b, s, h*128+d) f16 ----
#pragma unroll
    for (int jt = 0; jt < 8; ++jt) {
#pragma unroll
        for (int r = 0; r < 4; ++r) {
            int s = qabs + r;
            ob[((size_t)b * S_LEN + s) * EMB + h * HDIM + jt * 16 + frow] =
                (_Float16)(acco[jt][r] * inv[r]);
        }
    }
}

// ---------------------------------------------------------------------------
extern "C" void kernel_launch(void* const* d_in, const int* in_sizes, int n_in,
                              void* d_out, int out_size, void* d_ws, size_t ws_size,
                              hipStream_t stream) {
    const float* x     = (const float*)d_in[0];
    const float* w_qkv = (const float*)d_in[1];
    const float* w_out = (const float*)d_in[2];
    const float* w_c1  = (const float*)d_in[3];
    const float* w_c2  = (const float*)d_in[4];
    float* out = (float*)d_out;
    char* ws = (char*)d_ws;

    // ws layout (bytes). ao16 aliases wqkv16 (dead after gemm_qkv).
    double*    scal   = (double*)(ws + 0);
    int*       win    = (int*)(ws + 64);
    float*     xmean  = (float*)(ws + 128);
    float*     hidden = (float*)(ws + 16640);
    float2*    cstab  = (float2*)(ws + 32768);       // 2 MB
    _Float16*  x16    = (_Float16*)(ws + 4194304);   // 16.8 MB
    _Float16*  wqkv16 = (_Float16*)(ws + 20971520);  // 25.2 MB
    _Float16*  ao16   = (_Float16*)(ws + 20971520);  // alias
    _Float16*  v16t   = (_Float16*)(ws + 46137344);  // 16.8 MB
    _Float16*  q16    = (_Float16*)(ws + 62914560);  // 16.8 MB
    _Float16*  k16    = (_Float16*)(ws + 79691776);  // 16.8 MB
    _Float16*  wout16 = (_Float16*)(ws + 96468992);  // 8.4 MB

    hipMemsetAsync(d_ws, 0, 32768, stream);

    rope_table<<<dim3(S_LEN), dim3(HDIM), 0, stream>>>(cstab);
    col_reduce<<<dim3(2, 64, 2), dim3(256), 0, stream>>>(x, xmean, scal, x16);
    hidden_kernel<<<dim3(512, 2), dim3(256), 0, stream>>>(xmean, w_c1, hidden);
    window_kernel<<<dim3(1), dim3(512), 0, stream>>>(hidden, w_c2, scal, win);

    cvt_weights<<<dim3((NQKV4 + NOUT4) / 256), dim3(256), 0, stream>>>(
        w_qkv, w_out, wqkv16, wout16);

    gemm_qkv_f16<<<dim3(48, 32), dim3(256), 0, stream>>>(x16, wqkv16, q16, k16, v16t, cstab);
    attn_mfma<<<dim3(32, HEADS, 2), dim3(256), 0, stream>>>(q16, k16, v16t, ao16, win);
    gemm_out_f16<<<dim3(16, 32), dim3(256), 0, stream>>>(ao16, wout16, out);
}